// Round 3
// baseline (188.499 us; speedup 1.0000x reference)
//
#include <hip/hip_runtime.h>
#include <cmath>

// Problem constants
#define B_    16
#define N_    1024
#define NHID_ 32
#define NHEAD_ 4
#define NPRED_ 12
#define ALPHA 0.2f
#define NEGINF (-9e15f)

typedef __attribute__((ext_vector_type(8)))  short  short8;
typedef __attribute__((ext_vector_type(4)))  float  floatx4;

// bf16 bit-pattern helpers
__device__ __forceinline__ float bs2f(unsigned short s) {
    return __uint_as_float(((unsigned)s) << 16);
}
__device__ __forceinline__ short f2bs(float f) {
    unsigned u = __float_as_uint(f);
    unsigned r = (u + 0x7fffu + ((u >> 16) & 1u)) >> 16;  // RNE
    return (short)r;
}
// dtype-dispatched input load: isbf=1 -> bf16 bit pattern, else fp32
__device__ __forceinline__ float ldin(const void* p, long i, int isbf) {
    if (isbf) return bs2f(((const unsigned short*)p)[i]);
    return ((const float*)p)[i];
}

// ---------------------------------------------------------------------------
// k0: detect whether float inputs are bf16 or fp32 by exponent-field stats of
// x's first 1024 ushorts. bf16 N(0,1): exponent <= ~129, count(e>=160)=0.
// fp32: even-index shorts are mantissa halves -> e>=160 with ~37% prob.
// ---------------------------------------------------------------------------
__global__ __launch_bounds__(256) void k0_detect(const unsigned short* __restrict__ xu,
                                                 int* __restrict__ flag)
{
    __shared__ int cnt;
    if (threadIdx.x == 0) cnt = 0;
    __syncthreads();
    int c = 0;
    for (int i = threadIdx.x; i < 1024; i += 256) {
        unsigned e = (xu[i] >> 7) & 0xFFu;
        if (e >= 160u) ++c;
    }
    atomicAdd(&cnt, c);
    __syncthreads();
    if (threadIdx.x == 0) flag[0] = (cnt < 16) ? 1 : 0;   // 1 = bf16 inputs
}

// ---------------------------------------------------------------------------
// k1: Wh[b,h,n,k] = sum_f x[b,n,f]*W[h,f,k]  (fp32 accum)
//     f_src[bh,n] = Wh . a_src[h],  f_dst likewise (fp32)
//     WhB: Wh in 16x16x32 MFMA B-fragment order, 2 col-tiles (t = k>>4):
//       WhB[(((bh*32+kstep)*2+t)*64 + quad*16+(k&15))*8 + jj]
//         = Wh[bh][kstep*32 + quad*8 + jj][k]
// grid 8192 x 256: block = (bh, 8 rows); thread = (row r=tid>>5, k=tid&31)
// ---------------------------------------------------------------------------
__global__ __launch_bounds__(256) void k1_wh(
    const void* __restrict__ x, const void* __restrict__ W,
    const void* __restrict__ a_src, const void* __restrict__ a_dst,
    const int* __restrict__ flag,
    short* __restrict__ WhB, float* __restrict__ f_src, float* __restrict__ f_dst)
{
    __shared__ float Ws[16][32];
    __shared__ float xs[8][16];
    __shared__ float as_s[32], ad_s[32];
    int isbf = flag[0];
    int bid = blockIdx.x;
    int bh = bid >> 7;            // 0..63
    int n0 = (bid & 127) * 8;
    int b  = bh >> 2, hh = bh & 3;
    int tid = threadIdx.x;

    for (int idx = tid; idx < 512; idx += 256)
        Ws[idx >> 5][idx & 31] = ldin(W, hh * 512 + idx, isbf);
    if (tid < 32) {
        as_s[tid] = ldin(a_src, hh * 32 + tid, isbf);
        ad_s[tid] = ldin(a_dst, hh * 32 + tid, isbf);
    }
    if (tid < 128) {
        int r = tid >> 4, f = tid & 15;
        xs[r][f] = ldin(x, ((long)(b * N_ + n0 + r)) * 16 + f, isbf);
    }
    __syncthreads();

    int r = tid >> 5, k = tid & 31;
    float acc = 0.f;
#pragma unroll
    for (int f = 0; f < 16; ++f) acc += xs[r][f] * Ws[f][k];

    float t1 = acc * as_s[k], t2 = acc * ad_s[k];
#pragma unroll
    for (int m = 16; m; m >>= 1) {
        t1 += __shfl_xor(t1, m, 64);
        t2 += __shfl_xor(t2, m, 64);
    }
    int n = n0 + r;
    if (k == 0) {
        f_src[bh * N_ + n] = t1;
        f_dst[bh * N_ + n] = t2;
    }
    int kstep = n >> 5, quad = (n >> 3) & 3, jj = n & 7;
    int t = k >> 4, l = quad * 16 + (k & 15);
    WhB[((((size_t)bh * 32 + kstep) * 2 + t) * 64 + l) * 8 + jj] = f2bs(acc);
}

// ---------------------------------------------------------------------------
// k2: layer-1 attention. grid 1024 x 256. block = (bh, tile of 64 rows);
// each wave owns 16 rows: exact masked softmax stats, then K-chunked (128)
// normalized-P->LDS bf16 + mfma_16x16x32 over 2 col-tiles; ELU -> h_cat fp32.
// ---------------------------------------------------------------------------
__global__ __launch_bounds__(256) void k2_attn1(
    const float* __restrict__ f_src, const float* __restrict__ f_dst,
    const int* __restrict__ adj, const short* __restrict__ WhB,
    float* __restrict__ h_cat)
{
    __shared__ float fdst_s[N_];
    __shared__ float m_s[4][16], rs_s[4][16];
    __shared__ __align__(16) short p_s[4][16][136];  // 272B row stride, 16B-aligned
    int bid = blockIdx.x;
    int bh = bid >> 4;            // 0..63
    int tile = bid & 15;
    int tid = threadIdx.x;
    int w = tid >> 6, lane = tid & 63;

    for (int idx = tid; idx < N_; idx += 256) fdst_s[idx] = f_dst[bh * N_ + idx];
    __syncthreads();

    int i0 = tile * 64 + w * 16;

    for (int r = 0; r < 16; ++r) {
        int i = i0 + r;
        float fs = f_src[bh * N_ + i];
        const int* arow = adj + (size_t)i * N_;
        float sc[16];
        float M = -INFINITY;
#pragma unroll
        for (int jj = 0; jj < 16; ++jj) {
            int j = jj * 64 + lane;
            float v = fs + fdst_s[j];
            float e = v >= 0.f ? v : ALPHA * v;
            sc[jj] = arow[j] ? e : NEGINF;
            M = fmaxf(M, sc[jj]);
        }
#pragma unroll
        for (int m = 32; m; m >>= 1) M = fmaxf(M, __shfl_xor(M, m, 64));
        float S = 0.f;
#pragma unroll
        for (int jj = 0; jj < 16; ++jj) S += __expf(sc[jj] - M);
#pragma unroll
        for (int m = 32; m; m >>= 1) S += __shfl_xor(S, m, 64);
        if (lane == 0) { m_s[w][r] = M; rs_s[w][r] = 1.f / S; }
    }
    __syncthreads();

    floatx4 acc0 = {}, acc1 = {};
    for (int c = 0; c < 8; ++c) {
        int j0 = c * 128;
        for (int r = 0; r < 16; ++r) {
            int i = i0 + r;
            float fs = f_src[bh * N_ + i];
            float mrow = m_s[w][r], rs = rs_s[w][r];
            const int* arow = adj + (size_t)i * N_;
#pragma unroll
            for (int hlf = 0; hlf < 2; ++hlf) {
                int jl = hlf * 64 + lane;
                int j = j0 + jl;
                float v = fs + fdst_s[j];
                float e = v >= 0.f ? v : ALPHA * v;
                float scv = arow[j] ? e : NEGINF;
                float p = __expf(scv - mrow) * rs;   // normalized
                p_s[w][r][jl] = f2bs(p);
            }
        }
        __syncthreads();
        const short* prow = &p_s[w][lane & 15][0];
        int koff = (lane >> 4) * 8;
#pragma unroll
        for (int ks = 0; ks < 4; ++ks) {
            short8 afr = *(const short8*)(prow + ks * 32 + koff);
            const short* bbase = WhB + ((((size_t)bh * 32 + c * 4 + ks) * 2) * 64 + lane) * 8;
            short8 bfr0 = *(const short8*)(bbase);
            short8 bfr1 = *(const short8*)(bbase + 64 * 8);
            acc0 = __builtin_amdgcn_mfma_f32_16x16x32_bf16(afr, bfr0, acc0, 0, 0, 0);
            acc1 = __builtin_amdgcn_mfma_f32_16x16x32_bf16(afr, bfr1, acc1, 0, 0, 0);
        }
        __syncthreads();
    }

    int bb = bh >> 2, head = bh & 3;
    int col = lane & 15;
#pragma unroll
    for (int reg = 0; reg < 4; ++reg) {
        int row = (lane >> 4) * 4 + reg;
        float* hrow = &h_cat[((size_t)(bb * N_ + i0 + row)) * 128 + head * 32];
        float v0 = acc0[reg];
        hrow[col]      = v0 > 0.f ? v0 : expm1f(v0);
        float v1 = acc1[reg];
        hrow[16 + col] = v1 > 0.f ? v1 : expm1f(v1);
    }
}

// ---------------------------------------------------------------------------
// k3: Wh2 = h_cat @ W_out (128->12, pad to 16), g_src/g_dst, Wh2 scattered to
// 16x16x32 B-fragment layout. grid 1024 x 256: block = (b, 16 rows).
// ---------------------------------------------------------------------------
__global__ __launch_bounds__(256) void k3_out_proj(
    const float* __restrict__ h_cat, const void* __restrict__ W_out,
    const void* __restrict__ a_out_src, const void* __restrict__ a_out_dst,
    const int* __restrict__ flag,
    short* __restrict__ Wh2B, float* __restrict__ g_src, float* __restrict__ g_dst)
{
    __shared__ float Wo[128][16];
    __shared__ float hs[16][128];
    __shared__ float aos[16], aod[16];
    int isbf = flag[0];
    int bid = blockIdx.x;
    int b = bid >> 6;
    int n0 = (bid & 63) * 16;
    int tid = threadIdx.x;

    for (int idx = tid; idx < 2048; idx += 256) {
        int c = idx >> 4, p = idx & 15;
        Wo[c][p] = (p < NPRED_) ? ldin(W_out, c * NPRED_ + p, isbf) : 0.f;
    }
    if (tid < 16) {
        aos[tid] = (tid < NPRED_) ? ldin(a_out_src, tid, isbf) : 0.f;
        aod[tid] = (tid < NPRED_) ? ldin(a_out_dst, tid, isbf) : 0.f;
    }
    for (int idx = tid; idx < 2048; idx += 256) {
        int r = idx >> 7, c = idx & 127;
        hs[r][c] = h_cat[((size_t)(b * N_ + n0 + r)) * 128 + c];
    }
    __syncthreads();

    int r = tid >> 4, p = tid & 15;
    float acc = 0.f;
#pragma unroll 8
    for (int c = 0; c < 128; ++c) acc += hs[r][c] * Wo[c][p];

    float t1 = acc * aos[p], t2 = acc * aod[p];
#pragma unroll
    for (int m = 8; m; m >>= 1) {
        t1 += __shfl_xor(t1, m, 64);
        t2 += __shfl_xor(t2, m, 64);
    }
    int n = n0 + r;
    if (p == 0) {
        g_src[b * N_ + n] = t1;
        g_dst[b * N_ + n] = t2;
    }
    int kstep = n >> 5, quad = (n >> 3) & 3, jj = n & 7;
    Wh2B[(((size_t)b * 32 + kstep) * 64 + quad * 16 + p) * 8 + jj] = f2bs(acc);
}

// ---------------------------------------------------------------------------
// k4: layer-2 attention (H=1, Npred padded to 16). grid 256 x 256:
// block = (b, tile of 64 rows); each wave owns 16 rows. mfma 16x16x32.
// Epilogue: ELU -> d_out (bf16 or fp32 per flag).
// ---------------------------------------------------------------------------
__global__ __launch_bounds__(256) void k4_attn2(
    const float* __restrict__ g_src, const float* __restrict__ g_dst,
    const int* __restrict__ adj, const short* __restrict__ Wh2B,
    const int* __restrict__ flag, void* __restrict__ out)
{
    __shared__ float gdst_s[N_];
    __shared__ float m_s[4][16], rs_s[4][16];
    __shared__ __align__(16) short p_s[4][16][136];
    int isbf = flag[0];
    int bid = blockIdx.x;
    int b = bid >> 4;
    int tile = bid & 15;
    int tid = threadIdx.x;
    int w = tid >> 6, lane = tid & 63;

    for (int idx = tid; idx < N_; idx += 256) gdst_s[idx] = g_dst[b * N_ + idx];
    __syncthreads();

    int i0 = tile * 64 + w * 16;

    for (int r = 0; r < 16; ++r) {
        int i = i0 + r;
        float gs = g_src[b * N_ + i];
        const int* arow = adj + (size_t)i * N_;
        float sc[16];
        float M = -INFINITY;
#pragma unroll
        for (int jj = 0; jj < 16; ++jj) {
            int j = jj * 64 + lane;
            float v = gs + gdst_s[j];
            float e = v >= 0.f ? v : ALPHA * v;
            sc[jj] = arow[j] ? e : NEGINF;
            M = fmaxf(M, sc[jj]);
        }
#pragma unroll
        for (int m = 32; m; m >>= 1) M = fmaxf(M, __shfl_xor(M, m, 64));
        float S = 0.f;
#pragma unroll
        for (int jj = 0; jj < 16; ++jj) S += __expf(sc[jj] - M);
#pragma unroll
        for (int m = 32; m; m >>= 1) S += __shfl_xor(S, m, 64);
        if (lane == 0) { m_s[w][r] = M; rs_s[w][r] = 1.f / S; }
    }
    __syncthreads();

    floatx4 acc = {};
    for (int c = 0; c < 8; ++c) {
        int j0 = c * 128;
        for (int r = 0; r < 16; ++r) {
            int i = i0 + r;
            float gs = g_src[b * N_ + i];
            float mrow = m_s[w][r], rs = rs_s[w][r];
            const int* arow = adj + (size_t)i * N_;
#pragma unroll
            for (int hlf = 0; hlf < 2; ++hlf) {
                int jl = hlf * 64 + lane;
                int j = j0 + jl;
                float v = gs + gdst_s[j];
                float e = v >= 0.f ? v : ALPHA * v;
                float scv = arow[j] ? e : NEGINF;
                float p = __expf(scv - mrow) * rs;
                p_s[w][r][jl] = f2bs(p);
            }
        }
        __syncthreads();
        const short* prow = &p_s[w][lane & 15][0];
        int koff = (lane >> 4) * 8;
#pragma unroll
        for (int ks = 0; ks < 4; ++ks) {
            short8 afr = *(const short8*)(prow + ks * 32 + koff);
            short8 bfr = *(const short8*)(Wh2B + (((size_t)b * 32 + c * 4 + ks) * 64 + lane) * 8);
            acc = __builtin_amdgcn_mfma_f32_16x16x32_bf16(afr, bfr, acc, 0, 0, 0);
        }
        __syncthreads();
    }

    int col = lane & 15;
    if (col < NPRED_) {
#pragma unroll
        for (int reg = 0; reg < 4; ++reg) {
            int row = (lane >> 4) * 4 + reg;
            float v = acc[reg];
            float o = v > 0.f ? v : expm1f(v);
            size_t idx = (size_t)b * (N_ * NPRED_) + (size_t)(i0 + row) * NPRED_ + col;
            if (isbf) ((unsigned short*)out)[idx] = (unsigned short)f2bs(o);
            else      ((float*)out)[idx] = o;
        }
    }
}

// ---------------------------------------------------------------------------
extern "C" void kernel_launch(void* const* d_in, const int* in_sizes, int n_in,
                              void* d_out, int out_size, void* d_ws, size_t ws_size,
                              hipStream_t stream)
{
    (void)in_sizes; (void)n_in; (void)out_size; (void)ws_size;
    const void* x      = d_in[0];
    const int*  adj    = (const int*)d_in[1];
    const void* W      = d_in[2];
    const void* a_src  = d_in[3];
    const void* a_dst  = d_in[4];
    const void* W_out  = d_in[5];
    const void* a_osrc = d_in[6];
    const void* a_odst = d_in[7];

    char* ws = (char*)d_ws;
    short* WhB   = (short*)(ws);                                  // 4 MB
    float* f_src = (float*)(ws + (4 << 20));                      // 256 KB
    float* f_dst = (float*)(ws + (4 << 20) + (256 << 10));        // 256 KB
    float* h_cat = (float*)(ws + (4 << 20) + (512 << 10));        // 8 MB
    short* Wh2B  = (short*)(ws + (12 << 20) + (512 << 10));       // 512 KB
    float* g_src = (float*)(ws + (13 << 20));                     // 64 KB
    float* g_dst = (float*)(ws + (13 << 20) + (64 << 10));        // 64 KB
    int*   flag  = (int*)  (ws + (13 << 20) + (128 << 10));       // 4 B

    hipLaunchKernelGGL(k0_detect,  dim3(1),    dim3(256), 0, stream,
                       (const unsigned short*)x, flag);
    hipLaunchKernelGGL(k1_wh,      dim3(8192), dim3(256), 0, stream,
                       x, W, a_src, a_dst, flag, WhB, f_src, f_dst);
    hipLaunchKernelGGL(k2_attn1,   dim3(1024), dim3(256), 0, stream,
                       f_src, f_dst, adj, WhB, h_cat);
    hipLaunchKernelGGL(k3_out_proj,dim3(1024), dim3(256), 0, stream,
                       h_cat, W_out, a_osrc, a_odst, flag, Wh2B, g_src, g_dst);
    hipLaunchKernelGGL(k4_attn2,   dim3(256),  dim3(256), 0, stream,
                       g_src, g_dst, adj, Wh2B, flag, d_out);
}

// Round 4
// 151.649 us; speedup vs baseline: 1.2430x; 1.2430x over previous
//
#include <hip/hip_runtime.h>
#include <cmath>

// Problem constants
#define B_    16
#define N_    1024
#define NHID_ 32
#define NHEAD_ 4
#define NPRED_ 12
#define ALPHA 0.2f

typedef __attribute__((ext_vector_type(8)))  short  short8;
typedef __attribute__((ext_vector_type(4)))  float  floatx4;

// bf16 bit-pattern helpers
__device__ __forceinline__ float bs2f(unsigned short s) {
    return __uint_as_float(((unsigned)s) << 16);
}
__device__ __forceinline__ short f2bs(float f) {
    unsigned u = __float_as_uint(f);
    unsigned r = (u + 0x7fffu + ((u >> 16) & 1u)) >> 16;  // RNE
    return (short)r;
}
// dtype-dispatched input load: isbf=1 -> bf16 bit pattern, else fp32
__device__ __forceinline__ float ldin(const void* p, long i, int isbf) {
    if (isbf) return bs2f(((const unsigned short*)p)[i]);
    return ((const float*)p)[i];
}

// ---------------------------------------------------------------------------
// k0: (a) dtype detect (block 0) -> flag; (b) adj -> bf16 additive bias:
//     bias[i][j] = adj ? 0x0000 (0.0f) : 0xFF80 (-inf).   grid 512 x 256.
// ---------------------------------------------------------------------------
__global__ __launch_bounds__(256) void k0_prep(const unsigned short* __restrict__ xu,
                                               const int* __restrict__ adj,
                                               unsigned short* __restrict__ bias,
                                               int* __restrict__ flag)
{
    int gid = blockIdx.x * 256 + threadIdx.x;
    long base = (long)gid * 8;
    int4 a0 = *(const int4*)(adj + base);
    int4 a1 = *(const int4*)(adj + base + 4);
    uint4 wv;
    wv.x = (a0.x ? 0u : 0xFF80u) | (a0.y ? 0u : 0xFF800000u);
    wv.y = (a0.z ? 0u : 0xFF80u) | (a0.w ? 0u : 0xFF800000u);
    wv.z = (a1.x ? 0u : 0xFF80u) | (a1.y ? 0u : 0xFF800000u);
    wv.w = (a1.z ? 0u : 0xFF80u) | (a1.w ? 0u : 0xFF800000u);
    *(uint4*)(bias + base) = wv;

    if (blockIdx.x == 0) {
        __shared__ int cnt;
        if (threadIdx.x == 0) cnt = 0;
        __syncthreads();
        int c = 0;
        for (int i = threadIdx.x; i < 1024; i += 256) {
            unsigned e = (xu[i] >> 7) & 0xFFu;
            if (e >= 160u) ++c;
        }
        atomicAdd(&cnt, c);
        __syncthreads();
        if (threadIdx.x == 0) flag[0] = (cnt < 16) ? 1 : 0;   // 1 = bf16 inputs
    }
}

// ---------------------------------------------------------------------------
// k1: Wh = x@W (fp32), f_src/f_dst, WhB scatter (16x16x32 B-frag layout).
// grid 2048 x 256: block = (bh, 32 rows); thread = (row-slot=tid>>5, k=tid&31)
// x 4 row-groups of 8.
// ---------------------------------------------------------------------------
__global__ __launch_bounds__(256) void k1_wh(
    const void* __restrict__ x, const void* __restrict__ W,
    const void* __restrict__ a_src, const void* __restrict__ a_dst,
    const int* __restrict__ flag,
    short* __restrict__ WhB, float* __restrict__ f_src, float* __restrict__ f_dst)
{
    __shared__ float Ws[16][32];
    __shared__ float xs[32][16];
    __shared__ float as_s[32], ad_s[32];
    int isbf = flag[0];
    int bid = blockIdx.x;
    int bh = bid >> 5;            // 0..63
    int n0 = (bid & 31) * 32;
    int b  = bh >> 2, hh = bh & 3;
    int tid = threadIdx.x;

    for (int idx = tid; idx < 512; idx += 256)
        Ws[idx >> 5][idx & 31] = ldin(W, hh * 512 + idx, isbf);
    if (tid < 32) {
        as_s[tid] = ldin(a_src, hh * 32 + tid, isbf);
        ad_s[tid] = ldin(a_dst, hh * 32 + tid, isbf);
    }
    for (int idx = tid; idx < 512; idx += 256) {
        int r = idx >> 4, f = idx & 15;
        xs[r][f] = ldin(x, ((long)(b * N_ + n0 + r)) * 16 + f, isbf);
    }
    __syncthreads();

    int k = tid & 31, rb = tid >> 5;
#pragma unroll
    for (int it = 0; it < 4; ++it) {
        int r = it * 8 + rb;
        float acc = 0.f;
#pragma unroll
        for (int f = 0; f < 16; ++f) acc += xs[r][f] * Ws[f][k];

        float t1 = acc * as_s[k], t2 = acc * ad_s[k];
#pragma unroll
        for (int m = 16; m; m >>= 1) {
            t1 += __shfl_xor(t1, m, 64);
            t2 += __shfl_xor(t2, m, 64);
        }
        int n = n0 + r;
        if (k == 0) {
            f_src[bh * N_ + n] = t1;
            f_dst[bh * N_ + n] = t2;
        }
        int kstep = n >> 5, quad = (n >> 3) & 3, jj = n & 7;
        int t = k >> 4, l = quad * 16 + (k & 15);
        WhB[((((size_t)bh * 32 + kstep) * 2 + t) * 64 + l) * 8 + jj] = f2bs(acc);
    }
}

// ---------------------------------------------------------------------------
// k2: layer-1 attention, SINGLE PASS with fixed softmax bound.
// M_i = lrelu(f_src_i + max_j f_dst_j) >= every score (lrelu monotone).
// Accumulate unnormalized P via mfma; per-row S in regs; divide in epilogue.
// grid 1024 x 256: block = (bh, 64 rows); wave owns 16 rows.
// ---------------------------------------------------------------------------
__global__ __launch_bounds__(256) void k2_attn1(
    const float* __restrict__ f_src, const float* __restrict__ f_dst,
    const unsigned short* __restrict__ bias, const short* __restrict__ WhB,
    float* __restrict__ h_cat)
{
    __shared__ float fdst_s[N_];
    __shared__ float wmax[4];
    __shared__ float rs_s[4][16];
    __shared__ __align__(16) short p_s[4][16][136];
    int bid = blockIdx.x;
    int bh = bid >> 4;            // 0..63
    int tile = bid & 15;
    int tid = threadIdx.x;
    int w = tid >> 6, lane = tid & 63;

    float lmax = -INFINITY;
    for (int idx = tid; idx < N_; idx += 256) {
        float v = f_dst[bh * N_ + idx];
        fdst_s[idx] = v;
        lmax = fmaxf(lmax, v);
    }
#pragma unroll
    for (int m = 32; m; m >>= 1) lmax = fmaxf(lmax, __shfl_xor(lmax, m, 64));
    if (lane == 0) wmax[w] = lmax;
    __syncthreads();
    float maxfd = fmaxf(fmaxf(wmax[0], wmax[1]), fmaxf(wmax[2], wmax[3]));

    int i0 = tile * 64 + w * 16;

    float fsr[16], Mr[16], s_part[16];
#pragma unroll
    for (int r = 0; r < 16; ++r) {
        fsr[r] = f_src[bh * N_ + i0 + r];
        float M = fsr[r] + maxfd;
        Mr[r] = fmaxf(M, ALPHA * M);
        s_part[r] = 0.f;
    }

    floatx4 acc0 = {}, acc1 = {};
    const short* prow = &p_s[w][lane & 15][0];
    int koff = (lane >> 4) * 8;

    for (int c = 0; c < 8; ++c) {
        float2 fd2 = *(const float2*)&fdst_s[c * 128 + 2 * lane];
        const unsigned short* bptr = bias + (size_t)i0 * N_ + c * 128 + 2 * lane;
#pragma unroll
        for (int r = 0; r < 16; ++r) {
            unsigned bu = *(const unsigned*)(bptr + r * N_);
            float b0 = __uint_as_float(bu << 16);
            float b1 = __uint_as_float(bu & 0xffff0000u);
            float v0 = fsr[r] + fd2.x, v1 = fsr[r] + fd2.y;
            float e0 = fmaxf(v0, ALPHA * v0), e1 = fmaxf(v1, ALPHA * v1);
            float p0 = __expf(e0 + b0 - Mr[r]);   // masked: -inf -> 0
            float p1 = __expf(e1 + b1 - Mr[r]);
            s_part[r] += p0 + p1;
            unsigned u0 = __float_as_uint(p0) + 0x8000u;   // RTNA bf16
            unsigned u1 = __float_as_uint(p1) + 0x8000u;
            *(unsigned*)&p_s[w][r][2 * lane] = (u0 >> 16) | (u1 & 0xffff0000u);
        }
        __builtin_amdgcn_wave_barrier();
#pragma unroll
        for (int ks = 0; ks < 4; ++ks) {
            short8 afr = *(const short8*)(prow + ks * 32 + koff);
            const short* bbase = WhB + ((((size_t)bh * 32 + c * 4 + ks) * 2) * 64 + lane) * 8;
            short8 bfr0 = *(const short8*)(bbase);
            short8 bfr1 = *(const short8*)(bbase + 64 * 8);
            acc0 = __builtin_amdgcn_mfma_f32_16x16x32_bf16(afr, bfr0, acc0, 0, 0, 0);
            acc1 = __builtin_amdgcn_mfma_f32_16x16x32_bf16(afr, bfr1, acc1, 0, 0, 0);
        }
        __builtin_amdgcn_wave_barrier();
    }

#pragma unroll
    for (int r = 0; r < 16; ++r) {
        float s = s_part[r];
#pragma unroll
        for (int m = 32; m; m >>= 1) s += __shfl_xor(s, m, 64);
        if (lane == 0) rs_s[w][r] = 1.f / s;
    }
    __builtin_amdgcn_wave_barrier();

    int bb = bh >> 2, head = bh & 3;
    int col = lane & 15;
#pragma unroll
    for (int reg = 0; reg < 4; ++reg) {
        int row = (lane >> 4) * 4 + reg;
        float rsv = rs_s[w][row];
        float* hrow = &h_cat[((size_t)(bb * N_ + i0 + row)) * 128 + head * 32];
        float v0 = acc0[reg] * rsv;
        hrow[col]      = v0 > 0.f ? v0 : expm1f(v0);
        float v1 = acc1[reg] * rsv;
        hrow[16 + col] = v1 > 0.f ? v1 : expm1f(v1);
    }
}

// ---------------------------------------------------------------------------
// k3: Wh2 = h_cat @ W_out (128->12, pad 16), g_src/g_dst, Wh2B scatter.
// grid 1024 x 256: block = (b, 16 rows).
// ---------------------------------------------------------------------------
__global__ __launch_bounds__(256) void k3_out_proj(
    const float* __restrict__ h_cat, const void* __restrict__ W_out,
    const void* __restrict__ a_out_src, const void* __restrict__ a_out_dst,
    const int* __restrict__ flag,
    short* __restrict__ Wh2B, float* __restrict__ g_src, float* __restrict__ g_dst)
{
    __shared__ float Wo[128][16];
    __shared__ float hs[16][128];
    __shared__ float aos[16], aod[16];
    int isbf = flag[0];
    int bid = blockIdx.x;
    int b = bid >> 6;
    int n0 = (bid & 63) * 16;
    int tid = threadIdx.x;

    for (int idx = tid; idx < 2048; idx += 256) {
        int c = idx >> 4, p = idx & 15;
        Wo[c][p] = (p < NPRED_) ? ldin(W_out, c * NPRED_ + p, isbf) : 0.f;
    }
    if (tid < 16) {
        aos[tid] = (tid < NPRED_) ? ldin(a_out_src, tid, isbf) : 0.f;
        aod[tid] = (tid < NPRED_) ? ldin(a_out_dst, tid, isbf) : 0.f;
    }
    for (int idx = tid; idx < 512; idx += 256) {
        int r = idx >> 5, c4 = (idx & 31) * 4;
        *(float4*)&hs[r][c4] = *(const float4*)&h_cat[((size_t)(b * N_ + n0 + r)) * 128 + c4];
    }
    __syncthreads();

    int r = tid >> 4, p = tid & 15;
    float acc = 0.f;
#pragma unroll 8
    for (int c = 0; c < 128; ++c) acc += hs[r][c] * Wo[c][p];

    float t1 = acc * aos[p], t2 = acc * aod[p];
#pragma unroll
    for (int m = 8; m; m >>= 1) {
        t1 += __shfl_xor(t1, m, 64);
        t2 += __shfl_xor(t2, m, 64);
    }
    int n = n0 + r;
    if (p == 0) {
        g_src[b * N_ + n] = t1;
        g_dst[b * N_ + n] = t2;
    }
    int kstep = n >> 5, quad = (n >> 3) & 3, jj = n & 7;
    Wh2B[(((size_t)b * 32 + kstep) * 64 + quad * 16 + p) * 8 + jj] = f2bs(acc);
}

// ---------------------------------------------------------------------------
// k4: layer-2 attention, same single-pass structure. grid 256 x 256:
// block = (b, 64 rows); wave owns 16 rows. Epilogue: /S, ELU -> d_out.
// ---------------------------------------------------------------------------
__global__ __launch_bounds__(256) void k4_attn2(
    const float* __restrict__ g_src, const float* __restrict__ g_dst,
    const unsigned short* __restrict__ bias, const short* __restrict__ Wh2B,
    const int* __restrict__ flag, void* __restrict__ out)
{
    __shared__ float gdst_s[N_];
    __shared__ float wmax[4];
    __shared__ float rs_s[4][16];
    __shared__ __align__(16) short p_s[4][16][136];
    int isbf = flag[0];
    int bid = blockIdx.x;
    int b = bid >> 4;
    int tile = bid & 15;
    int tid = threadIdx.x;
    int w = tid >> 6, lane = tid & 63;

    float lmax = -INFINITY;
    for (int idx = tid; idx < N_; idx += 256) {
        float v = g_dst[b * N_ + idx];
        gdst_s[idx] = v;
        lmax = fmaxf(lmax, v);
    }
#pragma unroll
    for (int m = 32; m; m >>= 1) lmax = fmaxf(lmax, __shfl_xor(lmax, m, 64));
    if (lane == 0) wmax[w] = lmax;
    __syncthreads();
    float maxgd = fmaxf(fmaxf(wmax[0], wmax[1]), fmaxf(wmax[2], wmax[3]));

    int i0 = tile * 64 + w * 16;

    float gsr[16], Mr[16], s_part[16];
#pragma unroll
    for (int r = 0; r < 16; ++r) {
        gsr[r] = g_src[b * N_ + i0 + r];
        float M = gsr[r] + maxgd;
        Mr[r] = fmaxf(M, ALPHA * M);
        s_part[r] = 0.f;
    }

    floatx4 acc = {};
    const short* prow = &p_s[w][lane & 15][0];
    int koff = (lane >> 4) * 8;

    for (int c = 0; c < 8; ++c) {
        float2 fd2 = *(const float2*)&gdst_s[c * 128 + 2 * lane];
        const unsigned short* bptr = bias + (size_t)i0 * N_ + c * 128 + 2 * lane;
#pragma unroll
        for (int r = 0; r < 16; ++r) {
            unsigned bu = *(const unsigned*)(bptr + r * N_);
            float b0 = __uint_as_float(bu << 16);
            float b1 = __uint_as_float(bu & 0xffff0000u);
            float v0 = gsr[r] + fd2.x, v1 = gsr[r] + fd2.y;
            float e0 = fmaxf(v0, ALPHA * v0), e1 = fmaxf(v1, ALPHA * v1);
            float p0 = __expf(e0 + b0 - Mr[r]);
            float p1 = __expf(e1 + b1 - Mr[r]);
            s_part[r] += p0 + p1;
            unsigned u0 = __float_as_uint(p0) + 0x8000u;
            unsigned u1 = __float_as_uint(p1) + 0x8000u;
            *(unsigned*)&p_s[w][r][2 * lane] = (u0 >> 16) | (u1 & 0xffff0000u);
        }
        __builtin_amdgcn_wave_barrier();
#pragma unroll
        for (int ks = 0; ks < 4; ++ks) {
            short8 afr = *(const short8*)(prow + ks * 32 + koff);
            short8 bfr = *(const short8*)(Wh2B + (((size_t)b * 32 + c * 4 + ks) * 64 + lane) * 8);
            acc = __builtin_amdgcn_mfma_f32_16x16x32_bf16(afr, bfr, acc, 0, 0, 0);
        }
        __builtin_amdgcn_wave_barrier();
    }

#pragma unroll
    for (int r = 0; r < 16; ++r) {
        float s = s_part[r];
#pragma unroll
        for (int m = 32; m; m >>= 1) s += __shfl_xor(s, m, 64);
        if (lane == 0) rs_s[w][r] = 1.f / s;
    }
    __builtin_amdgcn_wave_barrier();

    int col = lane & 15;
    if (col < NPRED_) {
#pragma unroll
        for (int reg = 0; reg < 4; ++reg) {
            int row = (lane >> 4) * 4 + reg;
            float rsv = rs_s[w][row];
            float v = acc[reg] * rsv;
            float o = v > 0.f ? v : expm1f(v);
            size_t idx = (size_t)b * (N_ * NPRED_) + (size_t)(i0 + row) * NPRED_ + col;
            if (isbf) ((unsigned short*)out)[idx] = (unsigned short)f2bs(o);
            else      ((float*)out)[idx] = o;
        }
    }
}

// ---------------------------------------------------------------------------
extern "C" void kernel_launch(void* const* d_in, const int* in_sizes, int n_in,
                              void* d_out, int out_size, void* d_ws, size_t ws_size,
                              hipStream_t stream)
{
    (void)in_sizes; (void)n_in; (void)out_size; (void)ws_size;
    const void* x      = d_in[0];
    const int*  adj    = (const int*)d_in[1];
    const void* W      = d_in[2];
    const void* a_src  = d_in[3];
    const void* a_dst  = d_in[4];
    const void* W_out  = d_in[5];
    const void* a_osrc = d_in[6];
    const void* a_odst = d_in[7];

    char* ws = (char*)d_ws;
    short* WhB   = (short*)(ws);                                  // 4 MB
    float* f_src = (float*)(ws + (4 << 20));                      // 256 KB
    float* f_dst = (float*)(ws + (4 << 20) + (256 << 10));        // 256 KB
    float* h_cat = (float*)(ws + (4 << 20) + (512 << 10));        // 8 MB
    short* Wh2B  = (short*)(ws + (12 << 20) + (512 << 10));       // 512 KB
    float* g_src = (float*)(ws + (13 << 20));                     // 64 KB
    float* g_dst = (float*)(ws + (13 << 20) + (64 << 10));        // 64 KB
    int*   flag  = (int*)  (ws + (13 << 20) + (128 << 10));       // 4 B
    unsigned short* bias = (unsigned short*)(ws + (14 << 20));    // 2 MB

    hipLaunchKernelGGL(k0_prep,    dim3(512),  dim3(256), 0, stream,
                       (const unsigned short*)x, adj, bias, flag);
    hipLaunchKernelGGL(k1_wh,      dim3(2048), dim3(256), 0, stream,
                       x, W, a_src, a_dst, flag, WhB, f_src, f_dst);
    hipLaunchKernelGGL(k2_attn1,   dim3(1024), dim3(256), 0, stream,
                       f_src, f_dst, bias, WhB, h_cat);
    hipLaunchKernelGGL(k3_out_proj,dim3(1024), dim3(256), 0, stream,
                       h_cat, W_out, a_osrc, a_odst, flag, Wh2B, g_src, g_dst);
    hipLaunchKernelGGL(k4_attn2,   dim3(256),  dim3(256), 0, stream,
                       g_src, g_dst, bias, Wh2B, flag, d_out);
}

// Round 5
// 147.077 us; speedup vs baseline: 1.2816x; 1.0311x over previous
//
#include <hip/hip_runtime.h>
#include <cmath>

// Problem constants
#define B_    16
#define N_    1024
#define NHID_ 32
#define NHEAD_ 4
#define NPRED_ 12
#define ALPHA 0.2f
#define LOG2E 1.442695041f

typedef __attribute__((ext_vector_type(8)))  short  short8;
typedef __attribute__((ext_vector_type(4)))  float  floatx4;

// bf16 bit-pattern helpers
__device__ __forceinline__ float bs2f(unsigned short s) {
    return __uint_as_float(((unsigned)s) << 16);
}
__device__ __forceinline__ short f2bs(float f) {
    unsigned u = __float_as_uint(f);
    unsigned r = (u + 0x7fffu + ((u >> 16) & 1u)) >> 16;  // RNE
    return (short)r;
}
__device__ __forceinline__ float ldin(const void* p, long i, int isbf) {
    if (isbf) return bs2f(((const unsigned short*)p)[i]);
    return ((const float*)p)[i];
}
// 2^x, single v_exp_f32 when available
__device__ __forceinline__ float fexp2(float x) {
#if __has_builtin(__builtin_amdgcn_exp2f)
    return __builtin_amdgcn_exp2f(x);
#else
    return __expf(x * 0.6931471805599453f);
#endif
}
// pack two fp32 (already +0x8000 rounded) into bf16x2
__device__ __forceinline__ unsigned pk2(unsigned u0, unsigned u1) {
#if __has_builtin(__builtin_amdgcn_perm)
    return __builtin_amdgcn_perm(u1, u0, 0x07060302u);  // [u0.b2,u0.b3,u1.b2,u1.b3]
#else
    return (u0 >> 16) | (u1 & 0xffff0000u);
#endif
}

// ---------------------------------------------------------------------------
// k0: dtype detect (block 0) + adj -> bf16 additive bias (0 / -inf).
// ---------------------------------------------------------------------------
__global__ __launch_bounds__(256) void k0_prep(const unsigned short* __restrict__ xu,
                                               const int* __restrict__ adj,
                                               unsigned short* __restrict__ bias,
                                               int* __restrict__ flag)
{
    int gid = blockIdx.x * 256 + threadIdx.x;
    long base = (long)gid * 8;
    int4 a0 = *(const int4*)(adj + base);
    int4 a1 = *(const int4*)(adj + base + 4);
    uint4 wv;
    wv.x = (a0.x ? 0u : 0xFF80u) | (a0.y ? 0u : 0xFF800000u);
    wv.y = (a0.z ? 0u : 0xFF80u) | (a0.w ? 0u : 0xFF800000u);
    wv.z = (a1.x ? 0u : 0xFF80u) | (a1.y ? 0u : 0xFF800000u);
    wv.w = (a1.z ? 0u : 0xFF80u) | (a1.w ? 0u : 0xFF800000u);
    *(uint4*)(bias + base) = wv;

    if (blockIdx.x == 0) {
        __shared__ int cnt;
        if (threadIdx.x == 0) cnt = 0;
        __syncthreads();
        int c = 0;
        for (int i = threadIdx.x; i < 1024; i += 256) {
            unsigned e = (xu[i] >> 7) & 0xFFu;
            if (e >= 160u) ++c;
        }
        atomicAdd(&cnt, c);
        __syncthreads();
        if (threadIdx.x == 0) flag[0] = (cnt < 16) ? 1 : 0;   // 1 = bf16 inputs
    }
}

// ---------------------------------------------------------------------------
// k1: Wh = x@W (fp32), f_src/f_dst (pre-scaled by log2e), WhB scatter
// (16x16x32 B-frag). grid 2048 x 256: block = (bh, 32 rows).
// ---------------------------------------------------------------------------
__global__ __launch_bounds__(256) void k1_wh(
    const void* __restrict__ x, const void* __restrict__ W,
    const void* __restrict__ a_src, const void* __restrict__ a_dst,
    const int* __restrict__ flag,
    short* __restrict__ WhB, float* __restrict__ f_src, float* __restrict__ f_dst)
{
    __shared__ float Ws[16][32];
    __shared__ float xs[32][16];
    __shared__ float as_s[32], ad_s[32];
    int isbf = flag[0];
    int bid = blockIdx.x;
    int bh = bid >> 5;            // 0..63
    int n0 = (bid & 31) * 32;
    int b  = bh >> 2, hh = bh & 3;
    int tid = threadIdx.x;

    for (int idx = tid; idx < 512; idx += 256)
        Ws[idx >> 5][idx & 31] = ldin(W, hh * 512 + idx, isbf);
    if (tid < 32) {
        as_s[tid] = ldin(a_src, hh * 32 + tid, isbf);
        ad_s[tid] = ldin(a_dst, hh * 32 + tid, isbf);
    }
    for (int idx = tid; idx < 512; idx += 256) {
        int r = idx >> 4, f = idx & 15;
        xs[r][f] = ldin(x, ((long)(b * N_ + n0 + r)) * 16 + f, isbf);
    }
    __syncthreads();

    int k = tid & 31, rb = tid >> 5;
#pragma unroll
    for (int it = 0; it < 4; ++it) {
        int r = it * 8 + rb;
        float acc = 0.f;
#pragma unroll
        for (int f = 0; f < 16; ++f) acc += xs[r][f] * Ws[f][k];

        float t1 = acc * as_s[k], t2 = acc * ad_s[k];
#pragma unroll
        for (int m = 16; m; m >>= 1) {
            t1 += __shfl_xor(t1, m, 64);
            t2 += __shfl_xor(t2, m, 64);
        }
        int n = n0 + r;
        if (k == 0) {
            f_src[bh * N_ + n] = t1 * LOG2E;
            f_dst[bh * N_ + n] = t2 * LOG2E;
        }
        int kstep = n >> 5, quad = (n >> 3) & 3, jj = n & 7;
        int t = k >> 4, l = quad * 16 + (k & 15);
        WhB[((((size_t)bh * 32 + kstep) * 2 + t) * 64 + l) * 8 + jj] = f2bs(acc);
    }
}

// ---------------------------------------------------------------------------
// k2: layer-1 attention, single pass, log2 domain, column-split waves.
// grid 2048 x 256: block = (bh, 32 rows). wave w: rh=w&1 (row half, 16 rows),
// ch=w>>1 (4 of 8 column chunks). Partial S/acc combined in-block via LDS.
// ---------------------------------------------------------------------------
__global__ __launch_bounds__(256) void k2_attn1(
    const float* __restrict__ f_src, const float* __restrict__ f_dst,
    const unsigned short* __restrict__ bias, const short* __restrict__ WhB,
    float* __restrict__ h_cat)
{
    __shared__ float fdst_s[N_];
    __shared__ float wmax[4];
    __shared__ float Sh[2][2][16];
    __shared__ float xch[2][64][8];
    __shared__ __align__(16) short p_s[4][16][136];
    int bid = blockIdx.x;
    int bh = bid >> 5;            // 0..63
    int tile = bid & 31;
    int tid = threadIdx.x;
    int w = tid >> 6, lane = tid & 63;
    int rh = w & 1, ch = w >> 1;

    float lmax = -INFINITY;
    for (int idx = tid; idx < N_; idx += 256) {
        float v = f_dst[bh * N_ + idx];
        fdst_s[idx] = v;
        lmax = fmaxf(lmax, v);
    }
#pragma unroll
    for (int m = 32; m; m >>= 1) lmax = fmaxf(lmax, __shfl_xor(lmax, m, 64));
    if (lane == 0) wmax[w] = lmax;
    __syncthreads();
    float maxfd = fmaxf(fmaxf(wmax[0], wmax[1]), fmaxf(wmax[2], wmax[3]));

    int i0 = tile * 32 + rh * 16;

    float fsr[16], negM[16], s_part[16];
#pragma unroll
    for (int r = 0; r < 16; ++r) {
        fsr[r] = f_src[bh * N_ + i0 + r];
        float M = fsr[r] + maxfd;
        negM[r] = -fmaxf(M, ALPHA * M);
        s_part[r] = 0.f;
    }

    floatx4 acc0 = {}, acc1 = {};
    const short* prow = &p_s[w][lane & 15][0];
    int koff = (lane >> 4) * 8;

    for (int cc = 0; cc < 4; ++cc) {
        int c = ch * 4 + cc;
        float2 fd2 = *(const float2*)&fdst_s[c * 128 + 2 * lane];
        const unsigned short* bptr = bias + (size_t)i0 * N_ + c * 128 + 2 * lane;
        unsigned bu[16];
#pragma unroll
        for (int r = 0; r < 16; ++r) bu[r] = *(const unsigned*)(bptr + (size_t)r * N_);
#pragma unroll
        for (int r = 0; r < 16; ++r) {
            float b0 = __uint_as_float(bu[r] << 16);
            float b1 = __uint_as_float(bu[r] & 0xffff0000u);
            float v0 = fsr[r] + fd2.x, v1 = fsr[r] + fd2.y;
            float e0 = fmaxf(v0, ALPHA * v0), e1 = fmaxf(v1, ALPHA * v1);
            float p0 = fexp2(e0 + negM[r] + b0);   // masked: -inf -> 0
            float p1 = fexp2(e1 + negM[r] + b1);
            s_part[r] += p0 + p1;
            unsigned u0 = __float_as_uint(p0) + 0x8000u;   // RTNA bf16
            unsigned u1 = __float_as_uint(p1) + 0x8000u;
            *(unsigned*)&p_s[w][r][2 * lane] = pk2(u0, u1);
        }
        __builtin_amdgcn_wave_barrier();
#pragma unroll
        for (int ks = 0; ks < 4; ++ks) {
            short8 afr = *(const short8*)(prow + ks * 32 + koff);
            const short* bbase = WhB + ((((size_t)bh * 32 + c * 4 + ks) * 2) * 64 + lane) * 8;
            short8 bfr0 = *(const short8*)(bbase);
            short8 bfr1 = *(const short8*)(bbase + 64 * 8);
            acc0 = __builtin_amdgcn_mfma_f32_16x16x32_bf16(afr, bfr0, acc0, 0, 0, 0);
            acc1 = __builtin_amdgcn_mfma_f32_16x16x32_bf16(afr, bfr1, acc1, 0, 0, 0);
        }
        __builtin_amdgcn_wave_barrier();
    }

#pragma unroll
    for (int r = 0; r < 16; ++r) {
        float s = s_part[r];
#pragma unroll
        for (int m = 32; m; m >>= 1) s += __shfl_xor(s, m, 64);
        if (lane == 0) Sh[rh][ch][r] = s;
    }
    if (ch == 1) {
#pragma unroll
        for (int i = 0; i < 4; ++i) {
            xch[rh][lane][i]     = acc0[i];
            xch[rh][lane][4 + i] = acc1[i];
        }
    }
    __syncthreads();
    if (ch == 0) {
#pragma unroll
        for (int i = 0; i < 4; ++i) {
            acc0[i] += xch[rh][lane][i];
            acc1[i] += xch[rh][lane][4 + i];
        }
        int bb = bh >> 2, head = bh & 3;
        int col = lane & 15;
#pragma unroll
        for (int reg = 0; reg < 4; ++reg) {
            int row = (lane >> 4) * 4 + reg;
            float rsv = 1.f / (Sh[rh][0][row] + Sh[rh][1][row]);
            float* hrow = &h_cat[((size_t)(bb * N_ + i0 + row)) * 128 + head * 32];
            float v0 = acc0[reg] * rsv;
            hrow[col]      = v0 > 0.f ? v0 : expm1f(v0);
            float v1 = acc1[reg] * rsv;
            hrow[16 + col] = v1 > 0.f ? v1 : expm1f(v1);
        }
    }
}

// ---------------------------------------------------------------------------
// k3: Wh2 = h_cat @ W_out (128->12, pad 16), g_src/g_dst (log2e-scaled),
// Wh2B scatter. grid 1024 x 256: block = (b, 16 rows).
// ---------------------------------------------------------------------------
__global__ __launch_bounds__(256) void k3_out_proj(
    const float* __restrict__ h_cat, const void* __restrict__ W_out,
    const void* __restrict__ a_out_src, const void* __restrict__ a_out_dst,
    const int* __restrict__ flag,
    short* __restrict__ Wh2B, float* __restrict__ g_src, float* __restrict__ g_dst)
{
    __shared__ float Wo[128][16];
    __shared__ float hs[16][128];
    __shared__ float aos[16], aod[16];
    int isbf = flag[0];
    int bid = blockIdx.x;
    int b = bid >> 6;
    int n0 = (bid & 63) * 16;
    int tid = threadIdx.x;

    for (int idx = tid; idx < 2048; idx += 256) {
        int c = idx >> 4, p = idx & 15;
        Wo[c][p] = (p < NPRED_) ? ldin(W_out, c * NPRED_ + p, isbf) : 0.f;
    }
    if (tid < 16) {
        aos[tid] = (tid < NPRED_) ? ldin(a_out_src, tid, isbf) : 0.f;
        aod[tid] = (tid < NPRED_) ? ldin(a_out_dst, tid, isbf) : 0.f;
    }
    for (int idx = tid; idx < 512; idx += 256) {
        int r = idx >> 5, c4 = (idx & 31) * 4;
        *(float4*)&hs[r][c4] = *(const float4*)&h_cat[((size_t)(b * N_ + n0 + r)) * 128 + c4];
    }
    __syncthreads();

    int r = tid >> 4, p = tid & 15;
    float acc = 0.f;
#pragma unroll 8
    for (int c = 0; c < 128; ++c) acc += hs[r][c] * Wo[c][p];

    float t1 = acc * aos[p], t2 = acc * aod[p];
#pragma unroll
    for (int m = 8; m; m >>= 1) {
        t1 += __shfl_xor(t1, m, 64);
        t2 += __shfl_xor(t2, m, 64);
    }
    int n = n0 + r;
    if (p == 0) {
        g_src[b * N_ + n] = t1 * LOG2E;
        g_dst[b * N_ + n] = t2 * LOG2E;
    }
    int kstep = n >> 5, quad = (n >> 3) & 3, jj = n & 7;
    Wh2B[(((size_t)b * 32 + kstep) * 64 + quad * 16 + p) * 8 + jj] = f2bs(acc);
}

// ---------------------------------------------------------------------------
// k4: layer-2 attention, same single-pass column-split structure.
// grid 512 x 256: block = (b, 32 rows); wave (rh, ch).
// ---------------------------------------------------------------------------
__global__ __launch_bounds__(256) void k4_attn2(
    const float* __restrict__ g_src, const float* __restrict__ g_dst,
    const unsigned short* __restrict__ bias, const short* __restrict__ Wh2B,
    const int* __restrict__ flag, void* __restrict__ out)
{
    __shared__ float gdst_s[N_];
    __shared__ float wmax[4];
    __shared__ float Sh[2][2][16];
    __shared__ float xch[2][64][4];
    __shared__ __align__(16) short p_s[4][16][136];
    int isbf = flag[0];
    int bid = blockIdx.x;
    int b = bid >> 5;
    int tile = bid & 31;
    int tid = threadIdx.x;
    int w = tid >> 6, lane = tid & 63;
    int rh = w & 1, ch = w >> 1;

    float lmax = -INFINITY;
    for (int idx = tid; idx < N_; idx += 256) {
        float v = g_dst[b * N_ + idx];
        gdst_s[idx] = v;
        lmax = fmaxf(lmax, v);
    }
#pragma unroll
    for (int m = 32; m; m >>= 1) lmax = fmaxf(lmax, __shfl_xor(lmax, m, 64));
    if (lane == 0) wmax[w] = lmax;
    __syncthreads();
    float maxgd = fmaxf(fmaxf(wmax[0], wmax[1]), fmaxf(wmax[2], wmax[3]));

    int i0 = tile * 32 + rh * 16;

    float gsr[16], negM[16], s_part[16];
#pragma unroll
    for (int r = 0; r < 16; ++r) {
        gsr[r] = g_src[b * N_ + i0 + r];
        float M = gsr[r] + maxgd;
        negM[r] = -fmaxf(M, ALPHA * M);
        s_part[r] = 0.f;
    }

    floatx4 acc = {};
    const short* prow = &p_s[w][lane & 15][0];
    int koff = (lane >> 4) * 8;

    for (int cc = 0; cc < 4; ++cc) {
        int c = ch * 4 + cc;
        float2 fd2 = *(const float2*)&gdst_s[c * 128 + 2 * lane];
        const unsigned short* bptr = bias + (size_t)i0 * N_ + c * 128 + 2 * lane;
        unsigned bu[16];
#pragma unroll
        for (int r = 0; r < 16; ++r) bu[r] = *(const unsigned*)(bptr + (size_t)r * N_);
#pragma unroll
        for (int r = 0; r < 16; ++r) {
            float b0 = __uint_as_float(bu[r] << 16);
            float b1 = __uint_as_float(bu[r] & 0xffff0000u);
            float v0 = gsr[r] + fd2.x, v1 = gsr[r] + fd2.y;
            float e0 = fmaxf(v0, ALPHA * v0), e1 = fmaxf(v1, ALPHA * v1);
            float p0 = fexp2(e0 + negM[r] + b0);
            float p1 = fexp2(e1 + negM[r] + b1);
            s_part[r] += p0 + p1;
            unsigned u0 = __float_as_uint(p0) + 0x8000u;
            unsigned u1 = __float_as_uint(p1) + 0x8000u;
            *(unsigned*)&p_s[w][r][2 * lane] = pk2(u0, u1);
        }
        __builtin_amdgcn_wave_barrier();
#pragma unroll
        for (int ks = 0; ks < 4; ++ks) {
            short8 afr = *(const short8*)(prow + ks * 32 + koff);
            short8 bfr = *(const short8*)(Wh2B + (((size_t)b * 32 + c * 4 + ks) * 64 + lane) * 8);
            acc = __builtin_amdgcn_mfma_f32_16x16x32_bf16(afr, bfr, acc, 0, 0, 0);
        }
        __builtin_amdgcn_wave_barrier();
    }

#pragma unroll
    for (int r = 0; r < 16; ++r) {
        float s = s_part[r];
#pragma unroll
        for (int m = 32; m; m >>= 1) s += __shfl_xor(s, m, 64);
        if (lane == 0) Sh[rh][ch][r] = s;
    }
    if (ch == 1) {
#pragma unroll
        for (int i = 0; i < 4; ++i) xch[rh][lane][i] = acc[i];
    }
    __syncthreads();
    if (ch == 0) {
        int col = lane & 15;
#pragma unroll
        for (int i = 0; i < 4; ++i) acc[i] += xch[rh][lane][i];
        if (col < NPRED_) {
#pragma unroll
            for (int reg = 0; reg < 4; ++reg) {
                int row = (lane >> 4) * 4 + reg;
                float rsv = 1.f / (Sh[rh][0][row] + Sh[rh][1][row]);
                float v = acc[reg] * rsv;
                float o = v > 0.f ? v : expm1f(v);
                size_t idx = (size_t)b * (N_ * NPRED_) + (size_t)(i0 + row) * NPRED_ + col;
                if (isbf) ((unsigned short*)out)[idx] = (unsigned short)f2bs(o);
                else      ((float*)out)[idx] = o;
            }
        }
    }
}

// ---------------------------------------------------------------------------
extern "C" void kernel_launch(void* const* d_in, const int* in_sizes, int n_in,
                              void* d_out, int out_size, void* d_ws, size_t ws_size,
                              hipStream_t stream)
{
    (void)in_sizes; (void)n_in; (void)out_size; (void)ws_size;
    const void* x      = d_in[0];
    const int*  adj    = (const int*)d_in[1];
    const void* W      = d_in[2];
    const void* a_src  = d_in[3];
    const void* a_dst  = d_in[4];
    const void* W_out  = d_in[5];
    const void* a_osrc = d_in[6];
    const void* a_odst = d_in[7];

    char* ws = (char*)d_ws;
    short* WhB   = (short*)(ws);                                  // 4 MB
    float* f_src = (float*)(ws + (4 << 20));                      // 256 KB
    float* f_dst = (float*)(ws + (4 << 20) + (256 << 10));        // 256 KB
    float* h_cat = (float*)(ws + (4 << 20) + (512 << 10));        // 8 MB
    short* Wh2B  = (short*)(ws + (12 << 20) + (512 << 10));       // 512 KB
    float* g_src = (float*)(ws + (13 << 20));                     // 64 KB
    float* g_dst = (float*)(ws + (13 << 20) + (64 << 10));        // 64 KB
    int*   flag  = (int*)  (ws + (13 << 20) + (128 << 10));       // 4 B
    unsigned short* bias = (unsigned short*)(ws + (14 << 20));    // 2 MB

    hipLaunchKernelGGL(k0_prep,    dim3(512),  dim3(256), 0, stream,
                       (const unsigned short*)x, adj, bias, flag);
    hipLaunchKernelGGL(k1_wh,      dim3(2048), dim3(256), 0, stream,
                       x, W, a_src, a_dst, flag, WhB, f_src, f_dst);
    hipLaunchKernelGGL(k2_attn1,   dim3(2048), dim3(256), 0, stream,
                       f_src, f_dst, bias, WhB, h_cat);
    hipLaunchKernelGGL(k3_out_proj,dim3(1024), dim3(256), 0, stream,
                       h_cat, W_out, a_osrc, a_odst, flag, Wh2B, g_src, g_dst);
    hipLaunchKernelGGL(k4_attn2,   dim3(512),  dim3(256), 0, stream,
                       g_src, g_dst, bias, Wh2B, flag, d_out);
}

// Round 6
// 129.671 us; speedup vs baseline: 1.4537x; 1.1342x over previous
//
#include <hip/hip_runtime.h>
#include <cmath>

// Problem constants
#define B_    16
#define N_    1024
#define NHID_ 32
#define NHEAD_ 4
#define NPRED_ 12
#define ALPHA 0.2f
#define LOG2E 1.442695041f

typedef __attribute__((ext_vector_type(8)))  short    short8;
typedef __attribute__((ext_vector_type(4)))  float    floatx4;
typedef __attribute__((ext_vector_type(2)))  float    float2v;
typedef __attribute__((ext_vector_type(4)))  unsigned uintx4;

// bf16 bit-pattern helpers
__device__ __forceinline__ float bs2f(unsigned short s) {
    return __uint_as_float(((unsigned)s) << 16);
}
__device__ __forceinline__ short f2bs(float f) {
    unsigned u = __float_as_uint(f);
    unsigned r = (u + 0x7fffu + ((u >> 16) & 1u)) >> 16;  // RNE
    return (short)r;
}
__device__ __forceinline__ float ldin(const void* p, long i, int isbf) {
    if (isbf) return bs2f(((const unsigned short*)p)[i]);
    return ((const float*)p)[i];
}
__device__ __forceinline__ float fexp2(float x) {
#if __has_builtin(__builtin_amdgcn_exp2f)
    return __builtin_amdgcn_exp2f(x);
#else
    return __expf(x * 0.6931471805599453f);
#endif
}
// pack two fp32 (already +0x8000 rounded) into bf16x2 (low short = first arg)
__device__ __forceinline__ unsigned pk2(unsigned u0, unsigned u1) {
#if __has_builtin(__builtin_amdgcn_perm)
    return __builtin_amdgcn_perm(u1, u0, 0x07060302u);
#else
    return (u0 >> 16) | (u1 & 0xffff0000u);
#endif
}
__device__ __forceinline__ float2v vmax2(float2v a, float2v b) {
#if __has_builtin(__builtin_elementwise_max)
    return __builtin_elementwise_max(a, b);
#else
    float2v r; r.x = fmaxf(a.x, b.x); r.y = fmaxf(a.y, b.y); return r;
#endif
}
__device__ __forceinline__ float2v vfma2(float2v a, float2v b, float2v c) {
#if __has_builtin(__builtin_elementwise_fma)
    return __builtin_elementwise_fma(a, b, c);
#else
    float2v r; r.x = __builtin_fmaf(a.x, b.x, c.x); r.y = __builtin_fmaf(a.y, b.y, c.y); return r;
#endif
}
// per-block input-dtype detect from x's first 512 ushorts (wave-uniform).
// bf16 N(0,1): exponent field < 160 always. fp32: low-half shorts are mantissa
// bits -> exp field >= 160 w.p. ~0.37 each -> ~54 of 64 lanes see one.
__device__ __forceinline__ int detect_isbf(const unsigned short* xu) {
    int lane = threadIdx.x & 63;
    uint4 v = ((const uint4*)xu)[lane];
    unsigned wv[4] = {v.x, v.y, v.z, v.w};
    bool any = false;
#pragma unroll
    for (int i = 0; i < 4; ++i) {
        any |= (((wv[i] & 0xffffu) >> 7) & 0xffu) >= 160u;
        any |= (((wv[i] >> 16) >> 7) & 0xffu) >= 160u;
    }
    return __popcll(__ballot(any)) < 8;
}

// ---------------------------------------------------------------------------
// k01: fused prep. blocks 0..511: adj -> bf16 bias (0 / -inf).
// blocks 512..2559: k1 Wh = x@W, f_src/f_dst (log2e-scaled), WhB scatter
// (16x16x32 B-frag: WhB[(((bh*32+kstep)*2+t)*64 + quad*16+(k&15))*8 + jj]).
// ---------------------------------------------------------------------------
__global__ __launch_bounds__(256) void k01_prep_wh(
    const unsigned short* __restrict__ xu, const int* __restrict__ adj,
    const void* __restrict__ x, const void* __restrict__ W,
    const void* __restrict__ a_src, const void* __restrict__ a_dst,
    unsigned short* __restrict__ bias,
    short* __restrict__ WhB, float* __restrict__ f_src, float* __restrict__ f_dst)
{
    int tid = threadIdx.x;
    if (blockIdx.x < 512) {
        int gid = blockIdx.x * 256 + tid;
        long base = (long)gid * 8;
        int4 a0 = *(const int4*)(adj + base);
        int4 a1 = *(const int4*)(adj + base + 4);
        uint4 wv;
        wv.x = (a0.x ? 0u : 0xFF80u) | (a0.y ? 0u : 0xFF800000u);
        wv.y = (a0.z ? 0u : 0xFF80u) | (a0.w ? 0u : 0xFF800000u);
        wv.z = (a1.x ? 0u : 0xFF80u) | (a1.y ? 0u : 0xFF800000u);
        wv.w = (a1.z ? 0u : 0xFF80u) | (a1.w ? 0u : 0xFF800000u);
        *(uint4*)(bias + base) = wv;
        return;
    }
    int isbf = detect_isbf(xu);
    __shared__ float Ws[16][32];
    __shared__ float xs[32][16];
    __shared__ float as_s[32], ad_s[32];
    int bid = blockIdx.x - 512;
    int bh = bid >> 5;            // 0..63
    int n0 = (bid & 31) * 32;
    int b  = bh >> 2, hh = bh & 3;

    for (int idx = tid; idx < 512; idx += 256)
        Ws[idx >> 5][idx & 31] = ldin(W, hh * 512 + idx, isbf);
    if (tid < 32) {
        as_s[tid] = ldin(a_src, hh * 32 + tid, isbf);
        ad_s[tid] = ldin(a_dst, hh * 32 + tid, isbf);
    }
    for (int idx = tid; idx < 512; idx += 256) {
        int r = idx >> 4, f = idx & 15;
        xs[r][f] = ldin(x, ((long)(b * N_ + n0 + r)) * 16 + f, isbf);
    }
    __syncthreads();

    int k = tid & 31, rb = tid >> 5;
#pragma unroll
    for (int it = 0; it < 4; ++it) {
        int r = it * 8 + rb;
        float acc = 0.f;
#pragma unroll
        for (int f = 0; f < 16; ++f) acc += xs[r][f] * Ws[f][k];

        float t1 = acc * as_s[k], t2 = acc * ad_s[k];
#pragma unroll
        for (int m = 16; m; m >>= 1) {
            t1 += __shfl_xor(t1, m, 64);
            t2 += __shfl_xor(t2, m, 64);
        }
        int n = n0 + r;
        if (k == 0) {
            f_src[bh * N_ + n] = t1 * LOG2E;
            f_dst[bh * N_ + n] = t2 * LOG2E;
        }
        int kstep = n >> 5, quad = (n >> 3) & 3, jj = n & 7;
        int t = k >> 4, l = quad * 16 + (k & 15);
        WhB[((((size_t)bh * 32 + kstep) * 2 + t) * 64 + l) * 8 + jj] = f2bs(acc);
    }
}

// ---------------------------------------------------------------------------
// k2: layer-1 attention. A-fragment computed IN REGISTERS (no P LDS trip):
// lane (r=lane&15, q=lane>>4) computes P[i0+r][kk*32 + q*8 .. +8] directly in
// MFMA A-operand order. Single pass, log2 domain, packed-f32 math.
// grid 2048 x 256: block = (bh, 32 rows); wave (rh=w&1: row half, ch=w>>1:
// 16 of 32 K-steps). Partial acc/S combined via LDS.
// ---------------------------------------------------------------------------
__global__ __launch_bounds__(256) void k2_attn1(
    const float* __restrict__ f_src, const float* __restrict__ f_dst,
    const unsigned short* __restrict__ bias, const short* __restrict__ WhB,
    float* __restrict__ h_cat)
{
    __shared__ float fdst_s[N_];
    __shared__ float wmax[4];
    __shared__ float Sh[2][2][16];
    __shared__ float xch[2][64][8];
    int bid = blockIdx.x;
    int bh = bid >> 5;            // 0..63
    int tile = bid & 31;
    int tid = threadIdx.x;
    int w = tid >> 6, lane = tid & 63;
    int rh = w & 1, ch = w >> 1;

    float lmax = -INFINITY;
    for (int idx = tid; idx < N_; idx += 256) {
        float v = f_dst[bh * N_ + idx];
        fdst_s[idx] = v;
        lmax = fmaxf(lmax, v);
    }
#pragma unroll
    for (int m = 32; m; m >>= 1) lmax = fmaxf(lmax, __shfl_xor(lmax, m, 64));
    if (lane == 0) wmax[w] = lmax;
    __syncthreads();
    float maxfd = fmaxf(fmaxf(wmax[0], wmax[1]), fmaxf(wmax[2], wmax[3]));

    int i0 = tile * 32 + rh * 16;
    int r = lane & 15, q = lane >> 4;

    float fsr = f_src[bh * N_ + i0 + r];
    float Mv = fsr + maxfd;
    float M = fmaxf(Mv, ALPHA * Mv);            // upper bound on all scores
    float2v a1v; a1v.x = fsr - M;          a1v.y = a1v.x;   // (v - M) = a1 + fd
    float2v a2v; a2v.x = ALPHA * fsr - M;  a2v.y = a2v.x;   // (av - M) = fma(a,fd,a2)
    float2v alv; alv.x = ALPHA;            alv.y = ALPHA;
    float2v s2 = {};

    floatx4 acc0 = {}, acc1 = {};
    const unsigned short* brow = bias + (size_t)(i0 + r) * N_ + ch * 512 + q * 8;
    const float* fdp = fdst_s + ch * 512 + q * 8;

#pragma unroll 4
    for (int kk = 0; kk < 16; ++kk) {
        uint4 bu = *(const uint4*)(brow + kk * 32);
        float4 fda = *(const float4*)(fdp + kk * 32);
        float4 fdb = *(const float4*)(fdp + kk * 32 + 4);
        unsigned bw[4] = {bu.x, bu.y, bu.z, bu.w};
        float fdx[8] = {fda.x, fda.y, fda.z, fda.w, fdb.x, fdb.y, fdb.z, fdb.w};
        unsigned dpk[4];
#pragma unroll
        for (int p = 0; p < 4; ++p) {
            float2v fd2; fd2.x = fdx[2 * p]; fd2.y = fdx[2 * p + 1];
            float2v b2;  b2.x = __uint_as_float(bw[p] << 16);
                         b2.y = __uint_as_float(bw[p] & 0xffff0000u);
            float2v t1 = a1v + fd2;
            float2v t2 = vfma2(alv, fd2, a2v);
            float2v arg = vmax2(t1, t2) + b2;     // masked: -inf
            float2v pv; pv.x = fexp2(arg.x); pv.y = fexp2(arg.y);
            s2 += pv;
            dpk[p] = pk2(__float_as_uint(pv.x) + 0x8000u,
                         __float_as_uint(pv.y) + 0x8000u);
        }
        uintx4 du; du[0] = dpk[0]; du[1] = dpk[1]; du[2] = dpk[2]; du[3] = dpk[3];
        short8 afr = __builtin_bit_cast(short8, du);
        const short* bbase = WhB + ((((size_t)bh * 32 + ch * 16 + kk) * 2) * 64 + lane) * 8;
        short8 bfr0 = *(const short8*)(bbase);
        short8 bfr1 = *(const short8*)(bbase + 512);
        acc0 = __builtin_amdgcn_mfma_f32_16x16x32_bf16(afr, bfr0, acc0, 0, 0, 0);
        acc1 = __builtin_amdgcn_mfma_f32_16x16x32_bf16(afr, bfr1, acc1, 0, 0, 0);
    }

    float s = s2.x + s2.y;
    s += __shfl_xor(s, 16, 64);
    s += __shfl_xor(s, 32, 64);     // lanes {r,r+16,r+32,r+48} combined
    if (lane < 16) Sh[rh][ch][lane] = s;
    if (ch == 1) {
#pragma unroll
        for (int i = 0; i < 4; ++i) {
            xch[rh][lane][i]     = acc0[i];
            xch[rh][lane][4 + i] = acc1[i];
        }
    }
    __syncthreads();
    if (ch == 0) {
#pragma unroll
        for (int i = 0; i < 4; ++i) {
            acc0[i] += xch[rh][lane][i];
            acc1[i] += xch[rh][lane][4 + i];
        }
        int bb = bh >> 2, head = bh & 3;
#pragma unroll
        for (int reg = 0; reg < 4; ++reg) {
            int row = q * 4 + reg;
            float rsv = 1.f / (Sh[rh][0][row] + Sh[rh][1][row]);
            float* hrow = &h_cat[((size_t)(bb * N_ + i0 + row)) * 128 + head * 32];
            float v0 = acc0[reg] * rsv;
            hrow[r]      = v0 > 0.f ? v0 : expm1f(v0);
            float v1 = acc1[reg] * rsv;
            hrow[16 + r] = v1 > 0.f ? v1 : expm1f(v1);
        }
    }
}

// ---------------------------------------------------------------------------
// k3: Wh2 = h_cat @ W_out (128->12, pad 16; col15 = ONES for MFMA row-sum),
// g_src/g_dst (log2e-scaled), Wh2B scatter. grid 1024 x 256.
// ---------------------------------------------------------------------------
__global__ __launch_bounds__(256) void k3_out_proj(
    const unsigned short* __restrict__ xu,
    const float* __restrict__ h_cat, const void* __restrict__ W_out,
    const void* __restrict__ a_out_src, const void* __restrict__ a_out_dst,
    short* __restrict__ Wh2B, float* __restrict__ g_src, float* __restrict__ g_dst)
{
    int isbf = detect_isbf(xu);
    __shared__ float Wo[128][16];
    __shared__ float hs[16][128];
    __shared__ float aos[16], aod[16];
    int bid = blockIdx.x;
    int b = bid >> 6;
    int n0 = (bid & 63) * 16;
    int tid = threadIdx.x;

    for (int idx = tid; idx < 2048; idx += 256) {
        int c = idx >> 4, p = idx & 15;
        Wo[c][p] = (p < NPRED_) ? ldin(W_out, c * NPRED_ + p, isbf) : 0.f;
    }
    if (tid < 16) {
        aos[tid] = (tid < NPRED_) ? ldin(a_out_src, tid, isbf) : 0.f;
        aod[tid] = (tid < NPRED_) ? ldin(a_out_dst, tid, isbf) : 0.f;
    }
    for (int idx = tid; idx < 512; idx += 256) {
        int rr = idx >> 5, c4 = (idx & 31) * 4;
        *(float4*)&hs[rr][c4] = *(const float4*)&h_cat[((size_t)(b * N_ + n0 + rr)) * 128 + c4];
    }
    __syncthreads();

    int r = tid >> 4, p = tid & 15;
    float acc = 0.f;
#pragma unroll 8
    for (int c = 0; c < 128; ++c) acc += hs[r][c] * Wo[c][p];

    float t1 = acc * aos[p], t2 = acc * aod[p];
#pragma unroll
    for (int m = 8; m; m >>= 1) {
        t1 += __shfl_xor(t1, m, 64);
        t2 += __shfl_xor(t2, m, 64);
    }
    int n = n0 + r;
    if (p == 0) {
        g_src[b * N_ + n] = t1 * LOG2E;
        g_dst[b * N_ + n] = t2 * LOG2E;
    }
    int kstep = n >> 5, quad = (n >> 3) & 3, jj = n & 7;
    short val = (p == 15) ? (short)0x3F80 : f2bs(acc);   // ones column -> S
    Wh2B[(((size_t)b * 32 + kstep) * 64 + quad * 16 + p) * 8 + jj] = val;
}

// ---------------------------------------------------------------------------
// k4: layer-2 attention, in-register A-frag, S via ones-column (acc col 15).
// grid 1024 x 256: block = (b, 16 rows); wave ch=0..3 owns 8 K-steps.
// Partials combined in LDS; wave 0 does epilogue.
// ---------------------------------------------------------------------------
__global__ __launch_bounds__(256) void k4_attn2(
    const unsigned short* __restrict__ xu,
    const float* __restrict__ g_src, const float* __restrict__ g_dst,
    const unsigned short* __restrict__ bias, const short* __restrict__ Wh2B,
    void* __restrict__ out)
{
    int isbf = detect_isbf(xu);
    __shared__ float gdst_s[N_];
    __shared__ float wmax[4];
    __shared__ float xch[3][64][4];
    int bid = blockIdx.x;
    int b = bid >> 6;
    int tile = bid & 63;
    int tid = threadIdx.x;
    int ch = tid >> 6, lane = tid & 63;

    float lmax = -INFINITY;
    for (int idx = tid; idx < N_; idx += 256) {
        float v = g_dst[b * N_ + idx];
        gdst_s[idx] = v;
        lmax = fmaxf(lmax, v);
    }
#pragma unroll
    for (int m = 32; m; m >>= 1) lmax = fmaxf(lmax, __shfl_xor(lmax, m, 64));
    if (lane == 0) wmax[ch] = lmax;
    __syncthreads();
    float maxgd = fmaxf(fmaxf(wmax[0], wmax[1]), fmaxf(wmax[2], wmax[3]));

    int i0 = tile * 16;
    int r = lane & 15, q = lane >> 4;

    float gsr = g_src[b * N_ + i0 + r];
    float Mv = gsr + maxgd;
    float M = fmaxf(Mv, ALPHA * Mv);
    float2v a1v; a1v.x = gsr - M;          a1v.y = a1v.x;
    float2v a2v; a2v.x = ALPHA * gsr - M;  a2v.y = a2v.x;
    float2v alv; alv.x = ALPHA;            alv.y = ALPHA;

    floatx4 acc = {};
    const unsigned short* brow = bias + (size_t)(i0 + r) * N_ + ch * 256 + q * 8;
    const float* fdp = gdst_s + ch * 256 + q * 8;

#pragma unroll 4
    for (int kk = 0; kk < 8; ++kk) {
        uint4 bu = *(const uint4*)(brow + kk * 32);
        float4 fda = *(const float4*)(fdp + kk * 32);
        float4 fdb = *(const float4*)(fdp + kk * 32 + 4);
        unsigned bw[4] = {bu.x, bu.y, bu.z, bu.w};
        float fdx[8] = {fda.x, fda.y, fda.z, fda.w, fdb.x, fdb.y, fdb.z, fdb.w};
        unsigned dpk[4];
#pragma unroll
        for (int p = 0; p < 4; ++p) {
            float2v fd2; fd2.x = fdx[2 * p]; fd2.y = fdx[2 * p + 1];
            float2v b2;  b2.x = __uint_as_float(bw[p] << 16);
                         b2.y = __uint_as_float(bw[p] & 0xffff0000u);
            float2v t1 = a1v + fd2;
            float2v t2 = vfma2(alv, fd2, a2v);
            float2v arg = vmax2(t1, t2) + b2;
            float2v pv; pv.x = fexp2(arg.x); pv.y = fexp2(arg.y);
            dpk[p] = pk2(__float_as_uint(pv.x) + 0x8000u,
                         __float_as_uint(pv.y) + 0x8000u);
        }
        uintx4 du; du[0] = dpk[0]; du[1] = dpk[1]; du[2] = dpk[2]; du[3] = dpk[3];
        short8 afr = __builtin_bit_cast(short8, du);
        short8 bfr = *(const short8*)(Wh2B + (((size_t)b * 32 + ch * 8 + kk) * 64 + lane) * 8);
        acc = __builtin_amdgcn_mfma_f32_16x16x32_bf16(afr, bfr, acc, 0, 0, 0);
    }

    if (ch != 0) {
#pragma unroll
        for (int i = 0; i < 4; ++i) xch[ch - 1][lane][i] = acc[i];
    }
    __syncthreads();
    if (ch == 0) {
#pragma unroll
        for (int t = 0; t < 3; ++t)
#pragma unroll
            for (int i = 0; i < 4; ++i) acc[i] += xch[t][lane][i];
        // col 15 of acc = row sums S (ones column). Broadcast to row-holders.
        int srclane = (lane & 48) + 15;
#pragma unroll
        for (int reg = 0; reg < 4; ++reg) {
            int row = q * 4 + reg;
            float Srow = __shfl(acc[reg], srclane, 64);
            float v = acc[reg] / Srow;
            float o = v > 0.f ? v : expm1f(v);
            if (r < NPRED_) {
                size_t idx = (size_t)b * (N_ * NPRED_) + (size_t)(i0 + row) * NPRED_ + r;
                if (isbf) ((unsigned short*)out)[idx] = (unsigned short)f2bs(o);
                else      ((float*)out)[idx] = o;
            }
        }
    }
}

// ---------------------------------------------------------------------------
extern "C" void kernel_launch(void* const* d_in, const int* in_sizes, int n_in,
                              void* d_out, int out_size, void* d_ws, size_t ws_size,
                              hipStream_t stream)
{
    (void)in_sizes; (void)n_in; (void)out_size; (void)ws_size;
    const void* x      = d_in[0];
    const int*  adj    = (const int*)d_in[1];
    const void* W      = d_in[2];
    const void* a_src  = d_in[3];
    const void* a_dst  = d_in[4];
    const void* W_out  = d_in[5];
    const void* a_osrc = d_in[6];
    const void* a_odst = d_in[7];
    const unsigned short* xu = (const unsigned short*)x;

    char* ws = (char*)d_ws;
    short* WhB   = (short*)(ws);                                  // 4 MB
    float* f_src = (float*)(ws + (4 << 20));                      // 256 KB
    float* f_dst = (float*)(ws + (4 << 20) + (256 << 10));        // 256 KB
    float* h_cat = (float*)(ws + (4 << 20) + (512 << 10));        // 8 MB
    short* Wh2B  = (short*)(ws + (12 << 20) + (512 << 10));       // 512 KB
    float* g_src = (float*)(ws + (13 << 20));                     // 64 KB
    float* g_dst = (float*)(ws + (13 << 20) + (64 << 10));        // 64 KB
    unsigned short* bias = (unsigned short*)(ws + (14 << 20));    // 2 MB

    hipLaunchKernelGGL(k01_prep_wh, dim3(2560), dim3(256), 0, stream,
                       xu, adj, x, W, a_src, a_dst, bias, WhB, f_src, f_dst);
    hipLaunchKernelGGL(k2_attn1,    dim3(2048), dim3(256), 0, stream,
                       f_src, f_dst, bias, WhB, h_cat);
    hipLaunchKernelGGL(k3_out_proj, dim3(1024), dim3(256), 0, stream,
                       xu, h_cat, W_out, a_osrc, a_odst, Wh2B, g_src, g_dst);
    hipLaunchKernelGGL(k4_attn2,    dim3(1024), dim3(256), 0, stream,
                       xu, g_src, g_dst, bias, Wh2B, d_out);
}

// Round 7
// 127.163 us; speedup vs baseline: 1.4823x; 1.0197x over previous
//
#include <hip/hip_runtime.h>
#include <cmath>

// Problem constants
#define B_    16
#define N_    1024
#define NHID_ 32
#define NHEAD_ 4
#define NPRED_ 12
#define ALPHA 0.2f
#define LOG2E 1.442695041f

typedef __attribute__((ext_vector_type(8)))  short    short8;
typedef __attribute__((ext_vector_type(4)))  float    floatx4;
typedef __attribute__((ext_vector_type(2)))  float    float2v;
typedef __attribute__((ext_vector_type(4)))  unsigned uintx4;

// bf16 bit-pattern helpers
__device__ __forceinline__ float bs2f(unsigned short s) {
    return __uint_as_float(((unsigned)s) << 16);
}
__device__ __forceinline__ short f2bs(float f) {
    unsigned u = __float_as_uint(f);
    unsigned r = (u + 0x7fffu + ((u >> 16) & 1u)) >> 16;  // RNE
    return (short)r;
}
__device__ __forceinline__ float ldin(const void* p, long i, int isbf) {
    if (isbf) return bs2f(((const unsigned short*)p)[i]);
    return ((const float*)p)[i];
}
__device__ __forceinline__ float fexp2(float x) {
#if __has_builtin(__builtin_amdgcn_exp2f)
    return __builtin_amdgcn_exp2f(x);
#else
    return __expf(x * 0.6931471805599453f);
#endif
}
// pack two fp32 (already +0x8000 rounded) into bf16x2 (low short = first arg)
__device__ __forceinline__ unsigned pk2(unsigned u0, unsigned u1) {
#if __has_builtin(__builtin_amdgcn_perm)
    return __builtin_amdgcn_perm(u1, u0, 0x07060302u);
#else
    return (u0 >> 16) | (u1 & 0xffff0000u);
#endif
}
__device__ __forceinline__ float2v vmax2(float2v a, float2v b) {
#if __has_builtin(__builtin_elementwise_max)
    return __builtin_elementwise_max(a, b);
#else
    float2v r; r.x = fmaxf(a.x, b.x); r.y = fmaxf(a.y, b.y); return r;
#endif
}
__device__ __forceinline__ float2v vfma2(float2v a, float2v b, float2v c) {
#if __has_builtin(__builtin_elementwise_fma)
    return __builtin_elementwise_fma(a, b, c);
#else
    float2v r; r.x = __builtin_fmaf(a.x, b.x, c.x); r.y = __builtin_fmaf(a.y, b.y, c.y); return r;
#endif
}
// per-block input-dtype detect from x's first 512 ushorts (wave-uniform).
__device__ __forceinline__ int detect_isbf(const unsigned short* xu) {
    int lane = threadIdx.x & 63;
    uint4 v = ((const uint4*)xu)[lane];
    unsigned wv[4] = {v.x, v.y, v.z, v.w};
    bool any = false;
#pragma unroll
    for (int i = 0; i < 4; ++i) {
        any |= (((wv[i] & 0xffffu) >> 7) & 0xffu) >= 160u;
        any |= (((wv[i] >> 16) >> 7) & 0xffu) >= 160u;
    }
    return __popcll(__ballot(any)) < 8;
}

// ---------------------------------------------------------------------------
// k01: blocks 0..511: adj -> bf16 bias (0 / -inf).
// blocks 512..2559: Wh = x@W, f_src/f_dst via x·(W@a) (log2e-scaled),
// WhB scatter (16x16x32 B-frag).
// ---------------------------------------------------------------------------
__global__ __launch_bounds__(256) void k01_prep_wh(
    const unsigned short* __restrict__ xu, const int* __restrict__ adj,
    const void* __restrict__ x, const void* __restrict__ W,
    const void* __restrict__ a_src, const void* __restrict__ a_dst,
    unsigned short* __restrict__ bias,
    short* __restrict__ WhB, float* __restrict__ f_src, float* __restrict__ f_dst)
{
    int tid = threadIdx.x;
    if (blockIdx.x < 512) {
        int gid = blockIdx.x * 256 + tid;
        long base = (long)gid * 8;
        int4 a0 = *(const int4*)(adj + base);
        int4 a1 = *(const int4*)(adj + base + 4);
        uint4 wv;
        wv.x = (a0.x ? 0u : 0xFF80u) | (a0.y ? 0u : 0xFF800000u);
        wv.y = (a0.z ? 0u : 0xFF80u) | (a0.w ? 0u : 0xFF800000u);
        wv.z = (a1.x ? 0u : 0xFF80u) | (a1.y ? 0u : 0xFF800000u);
        wv.w = (a1.z ? 0u : 0xFF80u) | (a1.w ? 0u : 0xFF800000u);
        *(uint4*)(bias + base) = wv;
        return;
    }
    int isbf = detect_isbf(xu);
    __shared__ float Ws[16][32];
    __shared__ float xs[32][17];          // +1 pad: per-row dot would 16-way conflict
    __shared__ float as_s[32], ad_s[32];
    __shared__ float Wa_s[16], Wad_s[16];
    int bid = blockIdx.x - 512;
    int bh = bid >> 5;            // 0..63
    int n0 = (bid & 31) * 32;
    int b  = bh >> 2, hh = bh & 3;

    for (int idx = tid; idx < 512; idx += 256)
        Ws[idx >> 5][idx & 31] = ldin(W, hh * 512 + idx, isbf);
    if (tid < 32) {
        as_s[tid] = ldin(a_src, hh * 32 + tid, isbf);
        ad_s[tid] = ldin(a_dst, hh * 32 + tid, isbf);
    }
    for (int idx = tid; idx < 512; idx += 256) {
        int r = idx >> 4, f = idx & 15;
        xs[r][f] = ldin(x, ((long)(b * N_ + n0 + r)) * 16 + f, isbf);
    }
    __syncthreads();

    if (tid < 32) {                       // Wa = W@a (16 values each)
        int f = tid & 15;
        const float* av = (tid < 16) ? as_s : ad_s;
        float s = 0.f;
#pragma unroll
        for (int kk = 0; kk < 32; ++kk) s += Ws[f][kk] * av[kk];
        ((tid < 16) ? Wa_s : Wad_s)[f] = s;
    }
    __syncthreads();

    if (tid < 32) {                       // f_src[n] = x[n]·Wa  (no shuffles)
        float fs = 0.f, fd = 0.f;
#pragma unroll
        for (int f = 0; f < 16; ++f) {
            fs += xs[tid][f] * Wa_s[f];
            fd += xs[tid][f] * Wad_s[f];
        }
        int n = n0 + tid;
        f_src[bh * N_ + n] = fs * LOG2E;
        f_dst[bh * N_ + n] = fd * LOG2E;
    }

    int k = tid & 31, rb = tid >> 5;
#pragma unroll
    for (int it = 0; it < 4; ++it) {
        int r = it * 8 + rb;
        float acc = 0.f;
#pragma unroll
        for (int f = 0; f < 16; ++f) acc += xs[r][f] * Ws[f][k];
        int n = n0 + r;
        int kstep = n >> 5, quad = (n >> 3) & 3, jj = n & 7;
        int t = k >> 4, l = quad * 16 + (k & 15);
        WhB[((((size_t)bh * 32 + kstep) * 2 + t) * 64 + l) * 8 + jj] = f2bs(acc);
    }
}

// ---------------------------------------------------------------------------
// k2: layer-1 attention, in-register A-frag, single pass, log2 domain,
// distance-1 software prefetch of bias/fd. grid 2048 x 256.
// ---------------------------------------------------------------------------
__global__ __launch_bounds__(256) void k2_attn1(
    const float* __restrict__ f_src, const float* __restrict__ f_dst,
    const unsigned short* __restrict__ bias, const short* __restrict__ WhB,
    float* __restrict__ h_cat)
{
    __shared__ float fdst_s[N_];
    __shared__ float wmax[4];
    __shared__ float Sh[2][2][16];
    __shared__ float xch[2][64][8];
    int bid = blockIdx.x;
    int bh = bid >> 5;            // 0..63
    int tile = bid & 31;
    int tid = threadIdx.x;
    int w = tid >> 6, lane = tid & 63;
    int rh = w & 1, ch = w >> 1;

    float lmax = -INFINITY;
    for (int idx = tid; idx < N_; idx += 256) {
        float v = f_dst[bh * N_ + idx];
        fdst_s[idx] = v;
        lmax = fmaxf(lmax, v);
    }
#pragma unroll
    for (int m = 32; m; m >>= 1) lmax = fmaxf(lmax, __shfl_xor(lmax, m, 64));
    if (lane == 0) wmax[w] = lmax;
    __syncthreads();
    float maxfd = fmaxf(fmaxf(wmax[0], wmax[1]), fmaxf(wmax[2], wmax[3]));

    int i0 = tile * 32 + rh * 16;
    int r = lane & 15, q = lane >> 4;

    float fsr = f_src[bh * N_ + i0 + r];
    float Mv = fsr + maxfd;
    float M = fmaxf(Mv, ALPHA * Mv);
    float2v a1v; a1v.x = fsr - M;          a1v.y = a1v.x;
    float2v a2v; a2v.x = ALPHA * fsr - M;  a2v.y = a2v.x;
    float2v alv; alv.x = ALPHA;            alv.y = ALPHA;
    float2v s2 = {};

    floatx4 acc0 = {}, acc1 = {};
    const unsigned short* brow = bias + (size_t)(i0 + r) * N_ + ch * 512 + q * 8;
    const float* fdp = fdst_s + ch * 512 + q * 8;

    uint4  bu_n = *(const uint4*)(brow);
    float4 fa_n = *(const float4*)(fdp);
    float4 fb_n = *(const float4*)(fdp + 4);

#pragma unroll 4
    for (int kk = 0; kk < 16; ++kk) {
        uint4 bu = bu_n; float4 fda = fa_n; float4 fdb = fb_n;
        if (kk < 15) {
            bu_n = *(const uint4*)(brow + (kk + 1) * 32);
            fa_n = *(const float4*)(fdp + (kk + 1) * 32);
            fb_n = *(const float4*)(fdp + (kk + 1) * 32 + 4);
        }
        unsigned bw[4] = {bu.x, bu.y, bu.z, bu.w};
        float fdx[8] = {fda.x, fda.y, fda.z, fda.w, fdb.x, fdb.y, fdb.z, fdb.w};
        unsigned dpk[4];
#pragma unroll
        for (int p = 0; p < 4; ++p) {
            float2v fd2; fd2.x = fdx[2 * p]; fd2.y = fdx[2 * p + 1];
            float2v b2;  b2.x = __uint_as_float(bw[p] << 16);
                         b2.y = __uint_as_float(bw[p] & 0xffff0000u);
            float2v t1 = a1v + fd2;
            float2v t2 = vfma2(alv, fd2, a2v);
            float2v arg = vmax2(t1, t2) + b2;
            float2v pv; pv.x = fexp2(arg.x); pv.y = fexp2(arg.y);
            s2 += pv;
            dpk[p] = pk2(__float_as_uint(pv.x) + 0x8000u,
                         __float_as_uint(pv.y) + 0x8000u);
        }
        uintx4 du; du[0] = dpk[0]; du[1] = dpk[1]; du[2] = dpk[2]; du[3] = dpk[3];
        short8 afr = __builtin_bit_cast(short8, du);
        const short* bbase = WhB + ((((size_t)bh * 32 + ch * 16 + kk) * 2) * 64 + lane) * 8;
        short8 bfr0 = *(const short8*)(bbase);
        short8 bfr1 = *(const short8*)(bbase + 512);
        acc0 = __builtin_amdgcn_mfma_f32_16x16x32_bf16(afr, bfr0, acc0, 0, 0, 0);
        acc1 = __builtin_amdgcn_mfma_f32_16x16x32_bf16(afr, bfr1, acc1, 0, 0, 0);
    }

    float s = s2.x + s2.y;
    s += __shfl_xor(s, 16, 64);
    s += __shfl_xor(s, 32, 64);
    if (lane < 16) Sh[rh][ch][lane] = s;
    if (ch == 1) {
#pragma unroll
        for (int i = 0; i < 4; ++i) {
            xch[rh][lane][i]     = acc0[i];
            xch[rh][lane][4 + i] = acc1[i];
        }
    }
    __syncthreads();
    if (ch == 0) {
#pragma unroll
        for (int i = 0; i < 4; ++i) {
            acc0[i] += xch[rh][lane][i];
            acc1[i] += xch[rh][lane][4 + i];
        }
        int bb = bh >> 2, head = bh & 3;
#pragma unroll
        for (int reg = 0; reg < 4; ++reg) {
            int row = q * 4 + reg;
            float rsv = 1.f / (Sh[rh][0][row] + Sh[rh][1][row]);
            float* hrow = &h_cat[((size_t)(bb * N_ + i0 + row)) * 128 + head * 32];
            float v0 = acc0[reg] * rsv;
            hrow[r]      = v0 > 0.f ? v0 : expm1f(v0);
            float v1 = acc1[reg] * rsv;
            hrow[16 + r] = v1 > 0.f ? v1 : expm1f(v1);
        }
    }
}

// ---------------------------------------------------------------------------
// k3: Wh2 = h_cat @ W_out (transposed WoT + float4 LDS reads; col15 = ones),
// g_src/g_dst (log2e-scaled), Wh2B scatter. grid 1024 x 256.
// ---------------------------------------------------------------------------
__global__ __launch_bounds__(256) void k3_out_proj(
    const unsigned short* __restrict__ xu,
    const float* __restrict__ h_cat, const void* __restrict__ W_out,
    const void* __restrict__ a_out_src, const void* __restrict__ a_out_dst,
    short* __restrict__ Wh2B, float* __restrict__ g_src, float* __restrict__ g_dst)
{
    int isbf = detect_isbf(xu);
    __shared__ float WoT[16][132];        // 132: 16B-aligned rows, bank-staggered
    __shared__ float hs[16][132];
    __shared__ float aos[16], aod[16];
    int bid = blockIdx.x;
    int b = bid >> 6;
    int n0 = (bid & 63) * 16;
    int tid = threadIdx.x;

    for (int idx = tid; idx < 2048; idx += 256) {
        int p = idx >> 7, c = idx & 127;
        WoT[p][c] = (p < NPRED_) ? ldin(W_out, c * NPRED_ + p, isbf) : 0.f;
    }
    if (tid < 16) {
        aos[tid] = (tid < NPRED_) ? ldin(a_out_src, tid, isbf) : 0.f;
        aod[tid] = (tid < NPRED_) ? ldin(a_out_dst, tid, isbf) : 0.f;
    }
    for (int idx = tid; idx < 512; idx += 256) {
        int rr = idx >> 5, c4 = (idx & 31) * 4;
        *(float4*)&hs[rr][c4] = *(const float4*)&h_cat[((size_t)(b * N_ + n0 + rr)) * 128 + c4];
    }
    __syncthreads();

    int r = tid >> 4, p = tid & 15;
    float acc = 0.f;
#pragma unroll 8
    for (int c4 = 0; c4 < 128; c4 += 4) {
        float4 hv = *(const float4*)&hs[r][c4];
        float4 wv = *(const float4*)&WoT[p][c4];
        acc += hv.x * wv.x + hv.y * wv.y + hv.z * wv.z + hv.w * wv.w;
    }

    float t1 = acc * aos[p], t2 = acc * aod[p];
#pragma unroll
    for (int m = 8; m; m >>= 1) {
        t1 += __shfl_xor(t1, m, 64);
        t2 += __shfl_xor(t2, m, 64);
    }
    int n = n0 + r;
    if (p == 0) {
        g_src[b * N_ + n] = t1 * LOG2E;
        g_dst[b * N_ + n] = t2 * LOG2E;
    }
    int kstep = n >> 5, quad = (n >> 3) & 3, jj = n & 7;
    short val = (p == 15) ? (short)0x3F80 : f2bs(acc);   // ones column -> S
    Wh2B[(((size_t)b * 32 + kstep) * 64 + quad * 16 + p) * 8 + jj] = val;
}

// ---------------------------------------------------------------------------
// k4: layer-2 attention, in-register A-frag, S via ones-column, prefetch.
// grid 1024 x 256: block = (b, 16 rows); wave ch=0..3 owns 8 K-steps.
// ---------------------------------------------------------------------------
__global__ __launch_bounds__(256) void k4_attn2(
    const unsigned short* __restrict__ xu,
    const float* __restrict__ g_src, const float* __restrict__ g_dst,
    const unsigned short* __restrict__ bias, const short* __restrict__ Wh2B,
    void* __restrict__ out)
{
    int isbf = detect_isbf(xu);
    __shared__ float gdst_s[N_];
    __shared__ float wmax[4];
    __shared__ float xch[3][64][4];
    int bid = blockIdx.x;
    int b = bid >> 6;
    int tile = bid & 63;
    int tid = threadIdx.x;
    int ch = tid >> 6, lane = tid & 63;

    float lmax = -INFINITY;
    for (int idx = tid; idx < N_; idx += 256) {
        float v = g_dst[b * N_ + idx];
        gdst_s[idx] = v;
        lmax = fmaxf(lmax, v);
    }
#pragma unroll
    for (int m = 32; m; m >>= 1) lmax = fmaxf(lmax, __shfl_xor(lmax, m, 64));
    if (lane == 0) wmax[ch] = lmax;
    __syncthreads();
    float maxgd = fmaxf(fmaxf(wmax[0], wmax[1]), fmaxf(wmax[2], wmax[3]));

    int i0 = tile * 16;
    int r = lane & 15, q = lane >> 4;

    float gsr = g_src[b * N_ + i0 + r];
    float Mv = gsr + maxgd;
    float M = fmaxf(Mv, ALPHA * Mv);
    float2v a1v; a1v.x = gsr - M;          a1v.y = a1v.x;
    float2v a2v; a2v.x = ALPHA * gsr - M;  a2v.y = a2v.x;
    float2v alv; alv.x = ALPHA;            alv.y = ALPHA;

    floatx4 acc = {};
    const unsigned short* brow = bias + (size_t)(i0 + r) * N_ + ch * 256 + q * 8;
    const float* fdp = gdst_s + ch * 256 + q * 8;

    uint4  bu_n = *(const uint4*)(brow);
    float4 fa_n = *(const float4*)(fdp);
    float4 fb_n = *(const float4*)(fdp + 4);

#pragma unroll 4
    for (int kk = 0; kk < 8; ++kk) {
        uint4 bu = bu_n; float4 fda = fa_n; float4 fdb = fb_n;
        if (kk < 7) {
            bu_n = *(const uint4*)(brow + (kk + 1) * 32);
            fa_n = *(const float4*)(fdp + (kk + 1) * 32);
            fb_n = *(const float4*)(fdp + (kk + 1) * 32 + 4);
        }
        unsigned bw[4] = {bu.x, bu.y, bu.z, bu.w};
        float fdx[8] = {fda.x, fda.y, fda.z, fda.w, fdb.x, fdb.y, fdb.z, fdb.w};
        unsigned dpk[4];
#pragma unroll
        for (int p = 0; p < 4; ++p) {
            float2v fd2; fd2.x = fdx[2 * p]; fd2.y = fdx[2 * p + 1];
            float2v b2;  b2.x = __uint_as_float(bw[p] << 16);
                         b2.y = __uint_as_float(bw[p] & 0xffff0000u);
            float2v t1 = a1v + fd2;
            float2v t2 = vfma2(alv, fd2, a2v);
            float2v arg = vmax2(t1, t2) + b2;
            float2v pv; pv.x = fexp2(arg.x); pv.y = fexp2(arg.y);
            dpk[p] = pk2(__float_as_uint(pv.x) + 0x8000u,
                         __float_as_uint(pv.y) + 0x8000u);
        }
        uintx4 du; du[0] = dpk[0]; du[1] = dpk[1]; du[2] = dpk[2]; du[3] = dpk[3];
        short8 afr = __builtin_bit_cast(short8, du);
        short8 bfr = *(const short8*)(Wh2B + (((size_t)b * 32 + ch * 8 + kk) * 64 + lane) * 8);
        acc = __builtin_amdgcn_mfma_f32_16x16x32_bf16(afr, bfr, acc, 0, 0, 0);
    }

    if (ch != 0) {
#pragma unroll
        for (int i = 0; i < 4; ++i) xch[ch - 1][lane][i] = acc[i];
    }
    __syncthreads();
    if (ch == 0) {
#pragma unroll
        for (int t = 0; t < 3; ++t)
#pragma unroll
            for (int i = 0; i < 4; ++i) acc[i] += xch[t][lane][i];
        int srclane = (lane & 48) + 15;
#pragma unroll
        for (int reg = 0; reg < 4; ++reg) {
            int row = q * 4 + reg;
            float Srow = __shfl(acc[reg], srclane, 64);
            float v = acc[reg] / Srow;
            float o = v > 0.f ? v : expm1f(v);
            if (r < NPRED_) {
                size_t idx = (size_t)b * (N_ * NPRED_) + (size_t)(i0 + row) * NPRED_ + r;
                if (isbf) ((unsigned short*)out)[idx] = (unsigned short)f2bs(o);
                else      ((float*)out)[idx] = o;
            }
        }
    }
}

// ---------------------------------------------------------------------------
extern "C" void kernel_launch(void* const* d_in, const int* in_sizes, int n_in,
                              void* d_out, int out_size, void* d_ws, size_t ws_size,
                              hipStream_t stream)
{
    (void)in_sizes; (void)n_in; (void)out_size; (void)ws_size;
    const void* x      = d_in[0];
    const int*  adj    = (const int*)d_in[1];
    const void* W      = d_in[2];
    const void* a_src  = d_in[3];
    const void* a_dst  = d_in[4];
    const void* W_out  = d_in[5];
    const void* a_osrc = d_in[6];
    const void* a_odst = d_in[7];
    const unsigned short* xu = (const unsigned short*)x;

    char* ws = (char*)d_ws;
    short* WhB   = (short*)(ws);                                  // 4 MB
    float* f_src = (float*)(ws + (4 << 20));                      // 256 KB
    float* f_dst = (float*)(ws + (4 << 20) + (256 << 10));        // 256 KB
    float* h_cat = (float*)(ws + (4 << 20) + (512 << 10));        // 8 MB
    short* Wh2B  = (short*)(ws + (12 << 20) + (512 << 10));       // 512 KB
    float* g_src = (float*)(ws + (13 << 20));                     // 64 KB
    float* g_dst = (float*)(ws + (13 << 20) + (64 << 10));        // 64 KB
    unsigned short* bias = (unsigned short*)(ws + (14 << 20));    // 2 MB

    hipLaunchKernelGGL(k01_prep_wh, dim3(2560), dim3(256), 0, stream,
                       xu, adj, x, W, a_src, a_dst, bias, WhB, f_src, f_dst);
    hipLaunchKernelGGL(k2_attn1,    dim3(2048), dim3(256), 0, stream,
                       f_src, f_dst, bias, WhB, h_cat);
    hipLaunchKernelGGL(k3_out_proj, dim3(1024), dim3(256), 0, stream,
                       xu, h_cat, W_out, a_osrc, a_odst, Wh2B, g_src, g_dst);
    hipLaunchKernelGGL(k4_attn2,    dim3(1024), dim3(256), 0, stream,
                       xu, g_src, g_dst, bias, Wh2B, d_out);
}

// Round 8
// 120.769 us; speedup vs baseline: 1.5608x; 1.0529x over previous
//
#include <hip/hip_runtime.h>
#include <cmath>

// Problem constants
#define B_    16
#define N_    1024
#define NHID_ 32
#define NHEAD_ 4
#define NPRED_ 12
#define ALPHA 0.2f
#define LOG2E 1.442695041f

typedef __attribute__((ext_vector_type(8)))  short          short8;
typedef __attribute__((ext_vector_type(4)))  float          floatx4;
typedef __attribute__((ext_vector_type(2)))  float          float2v;
typedef __attribute__((ext_vector_type(4)))  unsigned       uintx4;
typedef __attribute__((ext_vector_type(4)))  unsigned short ushort4v;
typedef __attribute__((ext_vector_type(8)))  unsigned short ushort8v;

// bf16 bit-pattern helpers
__device__ __forceinline__ float bs2f(unsigned short s) {
    return __uint_as_float(((unsigned)s) << 16);
}
__device__ __forceinline__ short f2bs(float f) {
    unsigned u = __float_as_uint(f);
    unsigned r = (u + 0x7fffu + ((u >> 16) & 1u)) >> 16;  // RNE
    return (short)r;
}
__device__ __forceinline__ float ldin(const void* p, long i, int isbf) {
    if (isbf) return bs2f(((const unsigned short*)p)[i]);
    return ((const float*)p)[i];
}
__device__ __forceinline__ float fexp2(float x) {
#if __has_builtin(__builtin_amdgcn_exp2f)
    return __builtin_amdgcn_exp2f(x);
#else
    return __expf(x * 0.6931471805599453f);
#endif
}
// pack two fp32 (already +0x8000 rounded) into bf16x2 (low short = first arg)
__device__ __forceinline__ unsigned pk2(unsigned u0, unsigned u1) {
#if __has_builtin(__builtin_amdgcn_perm)
    return __builtin_amdgcn_perm(u1, u0, 0x07060302u);
#else
    return (u0 >> 16) | (u1 & 0xffff0000u);
#endif
}
__device__ __forceinline__ float2v vmax2(float2v a, float2v b) {
#if __has_builtin(__builtin_elementwise_max)
    return __builtin_elementwise_max(a, b);
#else
    float2v r; r.x = fmaxf(a.x, b.x); r.y = fmaxf(a.y, b.y); return r;
#endif
}
__device__ __forceinline__ float2v vfma2(float2v a, float2v b, float2v c) {
#if __has_builtin(__builtin_elementwise_fma)
    return __builtin_elementwise_fma(a, b, c);
#else
    float2v r; r.x = __builtin_fmaf(a.x, b.x, c.x); r.y = __builtin_fmaf(a.y, b.y, c.y); return r;
#endif
}
// per-block input-dtype detect from x's first 512 ushorts (wave-uniform).
__device__ __forceinline__ int detect_isbf(const unsigned short* xu) {
    int lane = threadIdx.x & 63;
    uint4 v = ((const uint4*)xu)[lane];
    unsigned wv[4] = {v.x, v.y, v.z, v.w};
    bool any = false;
#pragma unroll
    for (int i = 0; i < 4; ++i) {
        any |= (((wv[i] & 0xffffu) >> 7) & 0xffu) >= 160u;
        any |= (((wv[i] >> 16) >> 7) & 0xffu) >= 160u;
    }
    return __popcll(__ballot(any)) < 8;
}

// ---------------------------------------------------------------------------
// k01: blocks 0..511: adj -> bf16 bias (0 / -inf).
// blocks 512..2559: Wh = x@W, f_src/f_dst via x·(W@a) (log2e-scaled),
// WhB scatter (16x16x32 B-frag). Vectorized dtype-specialized staging.
// ---------------------------------------------------------------------------
__global__ __launch_bounds__(256) void k01_prep_wh(
    const unsigned short* __restrict__ xu, const int* __restrict__ adj,
    const void* __restrict__ x, const void* __restrict__ W,
    const void* __restrict__ a_src, const void* __restrict__ a_dst,
    unsigned short* __restrict__ bias,
    short* __restrict__ WhB, float* __restrict__ f_src, float* __restrict__ f_dst)
{
    int tid = threadIdx.x;
    if (blockIdx.x < 512) {
        int gid = blockIdx.x * 256 + tid;
        long base = (long)gid * 8;
        int4 a0 = *(const int4*)(adj + base);
        int4 a1 = *(const int4*)(adj + base + 4);
        uint4 wv;
        wv.x = (a0.x ? 0u : 0xFF80u) | (a0.y ? 0u : 0xFF800000u);
        wv.y = (a0.z ? 0u : 0xFF80u) | (a0.w ? 0u : 0xFF800000u);
        wv.z = (a1.x ? 0u : 0xFF80u) | (a1.y ? 0u : 0xFF800000u);
        wv.w = (a1.z ? 0u : 0xFF80u) | (a1.w ? 0u : 0xFF800000u);
        *(uint4*)(bias + base) = wv;
        return;
    }
    int isbf = detect_isbf(xu);
    __shared__ float Ws[16][32];
    __shared__ float xs[32][17];
    __shared__ float as_s[32], ad_s[32];
    __shared__ float Wa_s[16], Wad_s[16];
    int bid = blockIdx.x - 512;
    int bh = bid >> 5;            // 0..63
    int n0 = (bid & 31) * 32;
    int b  = bh >> 2, hh = bh & 3;

    if (!isbf) {
        const float* Wf = (const float*)W + hh * 512;
        if (tid < 128) {
            float4 v = *(const float4*)(Wf + tid * 4);
            int f = (tid * 4) >> 5, k = (tid * 4) & 31;
            Ws[f][k] = v.x; Ws[f][k+1] = v.y; Ws[f][k+2] = v.z; Ws[f][k+3] = v.w;
        }
        const float* xf = (const float*)x + ((long)(b * N_ + n0)) * 16;
        if (tid < 128) {
            float4 v = *(const float4*)(xf + tid * 4);
            int r = tid >> 2, f = (tid & 3) * 4;
            xs[r][f] = v.x; xs[r][f+1] = v.y; xs[r][f+2] = v.z; xs[r][f+3] = v.w;
        }
    } else {
        const unsigned short* Wb = (const unsigned short*)W + hh * 512;
        if (tid < 128) {
            ushort4v v = *(const ushort4v*)(Wb + tid * 4);
            int f = (tid * 4) >> 5, k = (tid * 4) & 31;
            Ws[f][k] = bs2f(v[0]); Ws[f][k+1] = bs2f(v[1]);
            Ws[f][k+2] = bs2f(v[2]); Ws[f][k+3] = bs2f(v[3]);
        }
        const unsigned short* xb = (const unsigned short*)x + ((long)(b * N_ + n0)) * 16;
        if (tid < 64) {
            ushort8v v = *(const ushort8v*)(xb + tid * 8);
            int r = tid >> 1, f = (tid & 1) * 8;
#pragma unroll
            for (int i = 0; i < 8; ++i) xs[r][f + i] = bs2f(v[i]);
        }
    }
    if (tid < 32) {
        as_s[tid] = ldin(a_src, hh * 32 + tid, isbf);
        ad_s[tid] = ldin(a_dst, hh * 32 + tid, isbf);
    }
    __syncthreads();

    if (tid < 32) {                       // Wa = W@a
        int f = tid & 15;
        const float* av = (tid < 16) ? as_s : ad_s;
        float s = 0.f;
#pragma unroll
        for (int kk = 0; kk < 32; ++kk) s += Ws[f][kk] * av[kk];
        ((tid < 16) ? Wa_s : Wad_s)[f] = s;
    }
    __syncthreads();

    if (tid < 32) {                       // f_src[n] = x[n]·Wa
        float fs = 0.f, fd = 0.f;
#pragma unroll
        for (int f = 0; f < 16; ++f) {
            fs += xs[tid][f] * Wa_s[f];
            fd += xs[tid][f] * Wad_s[f];
        }
        int n = n0 + tid;
        f_src[bh * N_ + n] = fs * LOG2E;
        f_dst[bh * N_ + n] = fd * LOG2E;
    }

    int k = tid & 31, rb = tid >> 5;
#pragma unroll
    for (int it = 0; it < 4; ++it) {
        int r = it * 8 + rb;
        float acc = 0.f;
#pragma unroll
        for (int f = 0; f < 16; ++f) acc += xs[r][f] * Ws[f][k];
        int n = n0 + r;
        int kstep = n >> 5, quad = (n >> 3) & 3, jj = n & 7;
        int t = k >> 4, l = quad * 16 + (k & 15);
        WhB[((((size_t)bh * 32 + kstep) * 2 + t) * 64 + l) * 8 + jj] = f2bs(acc);
    }
}

// ---------------------------------------------------------------------------
// k2: layer-1 attention, in-register A-frag, single pass, log2 domain,
// distance-1 prefetch. Tile-major block order (bias L2 reuse across bh).
// h written as bf16. grid 2048 x 256.
// ---------------------------------------------------------------------------
__global__ __launch_bounds__(256) void k2_attn1(
    const float* __restrict__ f_src, const float* __restrict__ f_dst,
    const unsigned short* __restrict__ bias, const short* __restrict__ WhB,
    unsigned short* __restrict__ h2)
{
    __shared__ float fdst_s[N_];
    __shared__ float wmax[4];
    __shared__ float Sh[2][2][16];
    __shared__ float xch[2][64][8];
    int bid = blockIdx.x;
    int bh = bid & 63;            // tile-major: consecutive blocks share tile
    int tile = bid >> 6;          // 0..31
    int tid = threadIdx.x;
    int w = tid >> 6, lane = tid & 63;
    int rh = w & 1, ch = w >> 1;

    float lmax = -INFINITY;
    for (int idx = tid; idx < N_; idx += 256) {
        float v = f_dst[bh * N_ + idx];
        fdst_s[idx] = v;
        lmax = fmaxf(lmax, v);
    }
#pragma unroll
    for (int m = 32; m; m >>= 1) lmax = fmaxf(lmax, __shfl_xor(lmax, m, 64));
    if (lane == 0) wmax[w] = lmax;
    __syncthreads();
    float maxfd = fmaxf(fmaxf(wmax[0], wmax[1]), fmaxf(wmax[2], wmax[3]));

    int i0 = tile * 32 + rh * 16;
    int r = lane & 15, q = lane >> 4;

    float fsr = f_src[bh * N_ + i0 + r];
    float Mv = fsr + maxfd;
    float M = fmaxf(Mv, ALPHA * Mv);
    float2v a1v; a1v.x = fsr - M;          a1v.y = a1v.x;
    float2v a2v; a2v.x = ALPHA * fsr - M;  a2v.y = a2v.x;
    float2v alv; alv.x = ALPHA;            alv.y = ALPHA;
    float2v s2 = {};

    floatx4 acc0 = {}, acc1 = {};
    const unsigned short* brow = bias + (size_t)(i0 + r) * N_ + ch * 512 + q * 8;
    const float* fdp = fdst_s + ch * 512 + q * 8;

    uint4  bu_n = *(const uint4*)(brow);
    float4 fa_n = *(const float4*)(fdp);
    float4 fb_n = *(const float4*)(fdp + 4);

#pragma unroll 4
    for (int kk = 0; kk < 16; ++kk) {
        uint4 bu = bu_n; float4 fda = fa_n; float4 fdb = fb_n;
        if (kk < 15) {
            bu_n = *(const uint4*)(brow + (kk + 1) * 32);
            fa_n = *(const float4*)(fdp + (kk + 1) * 32);
            fb_n = *(const float4*)(fdp + (kk + 1) * 32 + 4);
        }
        unsigned bw[4] = {bu.x, bu.y, bu.z, bu.w};
        float fdx[8] = {fda.x, fda.y, fda.z, fda.w, fdb.x, fdb.y, fdb.z, fdb.w};
        unsigned dpk[4];
#pragma unroll
        for (int p = 0; p < 4; ++p) {
            float2v fd2; fd2.x = fdx[2 * p]; fd2.y = fdx[2 * p + 1];
            float2v b2;  b2.x = __uint_as_float(bw[p] << 16);
                         b2.y = __uint_as_float(bw[p] & 0xffff0000u);
            float2v t1 = a1v + fd2;
            float2v t2 = vfma2(alv, fd2, a2v);
            float2v arg = vmax2(t1, t2) + b2;
            float2v pv; pv.x = fexp2(arg.x); pv.y = fexp2(arg.y);
            s2 += pv;
            dpk[p] = pk2(__float_as_uint(pv.x) + 0x8000u,
                         __float_as_uint(pv.y) + 0x8000u);
        }
        uintx4 du; du[0] = dpk[0]; du[1] = dpk[1]; du[2] = dpk[2]; du[3] = dpk[3];
        short8 afr = __builtin_bit_cast(short8, du);
        const short* bbase = WhB + ((((size_t)bh * 32 + ch * 16 + kk) * 2) * 64 + lane) * 8;
        short8 bfr0 = *(const short8*)(bbase);
        short8 bfr1 = *(const short8*)(bbase + 512);
        acc0 = __builtin_amdgcn_mfma_f32_16x16x32_bf16(afr, bfr0, acc0, 0, 0, 0);
        acc1 = __builtin_amdgcn_mfma_f32_16x16x32_bf16(afr, bfr1, acc1, 0, 0, 0);
    }

    float s = s2.x + s2.y;
    s += __shfl_xor(s, 16, 64);
    s += __shfl_xor(s, 32, 64);
    if (lane < 16) Sh[rh][ch][lane] = s;
    if (ch == 1) {
#pragma unroll
        for (int i = 0; i < 4; ++i) {
            xch[rh][lane][i]     = acc0[i];
            xch[rh][lane][4 + i] = acc1[i];
        }
    }
    __syncthreads();
    if (ch == 0) {
#pragma unroll
        for (int i = 0; i < 4; ++i) {
            acc0[i] += xch[rh][lane][i];
            acc1[i] += xch[rh][lane][4 + i];
        }
        int bb = bh >> 2, head = bh & 3;
#pragma unroll
        for (int reg = 0; reg < 4; ++reg) {
            int row = q * 4 + reg;
            float rsv = 1.f / (Sh[rh][0][row] + Sh[rh][1][row]);
            unsigned short* hrow = &h2[((size_t)(bb * N_ + i0 + row)) * 128 + head * 32];
            float v0 = acc0[reg] * rsv;
            v0 = v0 > 0.f ? v0 : expm1f(v0);
            hrow[r]      = (unsigned short)f2bs(v0);
            float v1 = acc1[reg] * rsv;
            v1 = v1 > 0.f ? v1 : expm1f(v1);
            hrow[16 + r] = (unsigned short)f2bs(v1);
        }
    }
}

// ---------------------------------------------------------------------------
// k3: Wh2 = h2(bf16) @ W_out (transposed WoT; col15 = ones), g_src/g_dst
// (log2e-scaled), Wh2B scatter. Vectorized staging. grid 1024 x 256.
// ---------------------------------------------------------------------------
__global__ __launch_bounds__(256) void k3_out_proj(
    const unsigned short* __restrict__ xu,
    const unsigned short* __restrict__ h2, const void* __restrict__ W_out,
    const void* __restrict__ a_out_src, const void* __restrict__ a_out_dst,
    short* __restrict__ Wh2B, float* __restrict__ g_src, float* __restrict__ g_dst)
{
    int isbf = detect_isbf(xu);
    __shared__ float WoT[16][132];
    __shared__ float hs[16][132];
    __shared__ float aos[16], aod[16];
    int bid = blockIdx.x;
    int b = bid >> 6;
    int n0 = (bid & 63) * 16;
    int tid = threadIdx.x;

    // W_out: 1536 elements, transposed into WoT[p][c]
    if (!isbf) {
        const float* Wf = (const float*)W_out;
        for (int idx = tid; idx < 384; idx += 256) {
            float4 v = *(const float4*)(Wf + idx * 4);
            float vv[4] = {v.x, v.y, v.z, v.w};
#pragma unroll
            for (int i = 0; i < 4; ++i) {
                int e = idx * 4 + i;
                WoT[e % NPRED_][e / NPRED_] = vv[i];
            }
        }
    } else {
        const unsigned short* Wb = (const unsigned short*)W_out;
        for (int idx = tid; idx < 192; idx += 256) {
            ushort8v v = *(const ushort8v*)(Wb + idx * 8);
#pragma unroll
            for (int i = 0; i < 8; ++i) {
                int e = idx * 8 + i;
                WoT[e % NPRED_][e / NPRED_] = bs2f(v[i]);
            }
        }
    }
    if (tid < 128) {
#pragma unroll
        for (int p = NPRED_; p < 16; ++p) WoT[p][tid] = 0.f;
    }
    if (tid < 16) {
        aos[tid] = (tid < NPRED_) ? ldin(a_out_src, tid, isbf) : 0.f;
        aod[tid] = (tid < NPRED_) ? ldin(a_out_dst, tid, isbf) : 0.f;
    }
    {   // h rows: 16 x 128 bf16 -> fp32 LDS
        ushort8v v = *(const ushort8v*)(h2 + ((size_t)(b * N_ + n0 + (tid >> 4))) * 128 + (tid & 15) * 8);
        int r = tid >> 4, c8 = (tid & 15) * 8;
#pragma unroll
        for (int i = 0; i < 8; ++i) hs[r][c8 + i] = bs2f(v[i]);
    }
    __syncthreads();

    int r = tid >> 4, p = tid & 15;
    float acc = 0.f;
#pragma unroll 8
    for (int c4 = 0; c4 < 128; c4 += 4) {
        float4 hv = *(const float4*)&hs[r][c4];
        float4 wv = *(const float4*)&WoT[p][c4];
        acc += hv.x * wv.x + hv.y * wv.y + hv.z * wv.z + hv.w * wv.w;
    }

    float t1 = acc * aos[p], t2 = acc * aod[p];
#pragma unroll
    for (int m = 8; m; m >>= 1) {
        t1 += __shfl_xor(t1, m, 64);
        t2 += __shfl_xor(t2, m, 64);
    }
    int n = n0 + r;
    if (p == 0) {
        g_src[b * N_ + n] = t1 * LOG2E;
        g_dst[b * N_ + n] = t2 * LOG2E;
    }
    int kstep = n >> 5, quad = (n >> 3) & 3, jj = n & 7;
    short val = (p == 15) ? (short)0x3F80 : f2bs(acc);   // ones column -> S
    Wh2B[(((size_t)b * 32 + kstep) * 64 + quad * 16 + p) * 8 + jj] = val;
}

// ---------------------------------------------------------------------------
// k4: layer-2 attention, in-register A-frag, S via ones-column, prefetch.
// Tile-major block order. grid 1024 x 256.
// ---------------------------------------------------------------------------
__global__ __launch_bounds__(256) void k4_attn2(
    const unsigned short* __restrict__ xu,
    const float* __restrict__ g_src, const float* __restrict__ g_dst,
    const unsigned short* __restrict__ bias, const short* __restrict__ Wh2B,
    void* __restrict__ out)
{
    int isbf = detect_isbf(xu);
    __shared__ float gdst_s[N_];
    __shared__ float wmax[4];
    __shared__ float xch[3][64][4];
    int bid = blockIdx.x;
    int b = bid & 15;             // tile-major
    int tile = bid >> 4;          // 0..63
    int tid = threadIdx.x;
    int ch = tid >> 6, lane = tid & 63;

    float lmax = -INFINITY;
    for (int idx = tid; idx < N_; idx += 256) {
        float v = g_dst[b * N_ + idx];
        gdst_s[idx] = v;
        lmax = fmaxf(lmax, v);
    }
#pragma unroll
    for (int m = 32; m; m >>= 1) lmax = fmaxf(lmax, __shfl_xor(lmax, m, 64));
    if (lane == 0) wmax[ch] = lmax;
    __syncthreads();
    float maxgd = fmaxf(fmaxf(wmax[0], wmax[1]), fmaxf(wmax[2], wmax[3]));

    int i0 = tile * 16;
    int r = lane & 15, q = lane >> 4;

    float gsr = g_src[b * N_ + i0 + r];
    float Mv = gsr + maxgd;
    float M = fmaxf(Mv, ALPHA * Mv);
    float2v a1v; a1v.x = gsr - M;          a1v.y = a1v.x;
    float2v a2v; a2v.x = ALPHA * gsr - M;  a2v.y = a2v.x;
    float2v alv; alv.x = ALPHA;            alv.y = ALPHA;

    floatx4 acc = {};
    const unsigned short* brow = bias + (size_t)(i0 + r) * N_ + ch * 256 + q * 8;
    const float* fdp = gdst_s + ch * 256 + q * 8;

    uint4  bu_n = *(const uint4*)(brow);
    float4 fa_n = *(const float4*)(fdp);
    float4 fb_n = *(const float4*)(fdp + 4);

#pragma unroll 4
    for (int kk = 0; kk < 8; ++kk) {
        uint4 bu = bu_n; float4 fda = fa_n; float4 fdb = fb_n;
        if (kk < 7) {
            bu_n = *(const uint4*)(brow + (kk + 1) * 32);
            fa_n = *(const float4*)(fdp + (kk + 1) * 32);
            fb_n = *(const float4*)(fdp + (kk + 1) * 32 + 4);
        }
        unsigned bw[4] = {bu.x, bu.y, bu.z, bu.w};
        float fdx[8] = {fda.x, fda.y, fda.z, fda.w, fdb.x, fdb.y, fdb.z, fdb.w};
        unsigned dpk[4];
#pragma unroll
        for (int p = 0; p < 4; ++p) {
            float2v fd2; fd2.x = fdx[2 * p]; fd2.y = fdx[2 * p + 1];
            float2v b2;  b2.x = __uint_as_float(bw[p] << 16);
                         b2.y = __uint_as_float(bw[p] & 0xffff0000u);
            float2v t1 = a1v + fd2;
            float2v t2 = vfma2(alv, fd2, a2v);
            float2v arg = vmax2(t1, t2) + b2;
            float2v pv; pv.x = fexp2(arg.x); pv.y = fexp2(arg.y);
            dpk[p] = pk2(__float_as_uint(pv.x) + 0x8000u,
                         __float_as_uint(pv.y) + 0x8000u);
        }
        uintx4 du; du[0] = dpk[0]; du[1] = dpk[1]; du[2] = dpk[2]; du[3] = dpk[3];
        short8 afr = __builtin_bit_cast(short8, du);
        short8 bfr = *(const short8*)(Wh2B + (((size_t)b * 32 + ch * 8 + kk) * 64 + lane) * 8);
        acc = __builtin_amdgcn_mfma_f32_16x16x32_bf16(afr, bfr, acc, 0, 0, 0);
    }

    if (ch != 0) {
#pragma unroll
        for (int i = 0; i < 4; ++i) xch[ch - 1][lane][i] = acc[i];
    }
    __syncthreads();
    if (ch == 0) {
#pragma unroll
        for (int t = 0; t < 3; ++t)
#pragma unroll
            for (int i = 0; i < 4; ++i) acc[i] += xch[t][lane][i];
        int srclane = (lane & 48) + 15;
#pragma unroll
        for (int reg = 0; reg < 4; ++reg) {
            int row = q * 4 + reg;
            float Srow = __shfl(acc[reg], srclane, 64);
            float v = acc[reg] / Srow;
            float o = v > 0.f ? v : expm1f(v);
            if (r < NPRED_) {
                size_t idx = (size_t)b * (N_ * NPRED_) + (size_t)(i0 + row) * NPRED_ + r;
                if (isbf) ((unsigned short*)out)[idx] = (unsigned short)f2bs(o);
                else      ((float*)out)[idx] = o;
            }
        }
    }
}

// ---------------------------------------------------------------------------
extern "C" void kernel_launch(void* const* d_in, const int* in_sizes, int n_in,
                              void* d_out, int out_size, void* d_ws, size_t ws_size,
                              hipStream_t stream)
{
    (void)in_sizes; (void)n_in; (void)out_size; (void)ws_size;
    const void* x      = d_in[0];
    const int*  adj    = (const int*)d_in[1];
    const void* W      = d_in[2];
    const void* a_src  = d_in[3];
    const void* a_dst  = d_in[4];
    const void* W_out  = d_in[5];
    const void* a_osrc = d_in[6];
    const void* a_odst = d_in[7];
    const unsigned short* xu = (const unsigned short*)x;

    char* ws = (char*)d_ws;
    short* WhB   = (short*)(ws);                                  // 4 MB
    float* f_src = (float*)(ws + (4 << 20));                      // 256 KB
    float* f_dst = (float*)(ws + (4 << 20) + (256 << 10));        // 256 KB
    unsigned short* h2 = (unsigned short*)(ws + (4 << 20) + (512 << 10)); // 4 MB
    short* Wh2B  = (short*)(ws + (12 << 20) + (512 << 10));       // 512 KB
    float* g_src = (float*)(ws + (13 << 20));                     // 64 KB
    float* g_dst = (float*)(ws + (13 << 20) + (64 << 10));        // 64 KB
    unsigned short* bias = (unsigned short*)(ws + (14 << 20));    // 2 MB

    hipLaunchKernelGGL(k01_prep_wh, dim3(2560), dim3(256), 0, stream,
                       xu, adj, x, W, a_src, a_dst, bias, WhB, f_src, f_dst);
    hipLaunchKernelGGL(k2_attn1,    dim3(2048), dim3(256), 0, stream,
                       f_src, f_dst, bias, WhB, h2);
    hipLaunchKernelGGL(k3_out_proj, dim3(1024), dim3(256), 0, stream,
                       xu, h2, W_out, a_osrc, a_odst, Wh2B, g_src, g_dst);
    hipLaunchKernelGGL(k4_attn2,    dim3(1024), dim3(256), 0, stream,
                       xu, g_src, g_dst, bias, Wh2B, d_out);
}